// Round 5
// baseline (1583.953 us; speedup 1.0000x reference)
//
#include <hip/hip_runtime.h>
#include <math.h>

#define NRES 8192
#define NPER 2048
#define KNB  30
#define NEDGE (NRES*KNB)

typedef float v2f __attribute__((ext_vector_type(2)));

__device__ __forceinline__ float siluf(float x){ return x / (1.0f + __expf(-x)); }
__device__ __forceinline__ v2f splat2(float a){ v2f r; r.x=a; r.y=a; return r; }

// quad broadcast: value of lane (quadbase+Q) to all 4 lanes of the quad (VALU DPP, no LDS)
template<int Q>
__device__ __forceinline__ float qb(float v){
  return __int_as_float(__builtin_amdgcn_mov_dpp(__float_as_int(v), Q*0x55, 0xF, 0xF, true));
}

// ---------------- K0: backbone features + ca pack ----------------
__global__ void k_bbfeat(const float* __restrict__ bb, float* __restrict__ bbf,
                         float4* __restrict__ ca){
  int n = blockIdx.x*256 + threadIdx.x;
  if(n >= NRES) return;
  const float* r = bb + n*12;
  float cax=r[3], cay=r[4], caz=r[5];
  ca[n] = make_float4(cax,cay,caz, cax*cax+cay*cay+caz*caz);
  float vx[7],vy[7],vz[7];
  for(int a=0;a<4;a++){ vx[a]=r[a*3]-cax; vy[a]=r[a*3+1]-cay; vz[a]=r[a*3+2]-caz; }
  if(n<NRES-1){
    float dx=bb[(n+1)*12+3]-cax, dy=bb[(n+1)*12+4]-cay, dz=bb[(n+1)*12+5]-caz;
    float s=rsqrtf(dx*dx+dy*dy+dz*dz+1e-8f);
    vx[4]=dx*s; vy[4]=dy*s; vz[4]=dz*s;
  } else { vx[4]=0.f; vy[4]=0.f; vz[4]=0.f; }
  if(n>0){
    float dx=bb[(n-1)*12+3]-cax, dy=bb[(n-1)*12+4]-cay, dz=bb[(n-1)*12+5]-caz;
    float s=rsqrtf(dx*dx+dy*dy+dz*dz+1e-8f);
    vx[5]=dx*s; vy[5]=dy*s; vz[5]=dz*s;
  } else { vx[5]=0.f; vy[5]=0.f; vz[5]=0.f; }
  {
    float bx=cax-r[0], by=cay-r[1], bz=caz-r[2];
    float cx=r[6]-cax, cy=r[7]-cay, cz=r[8]-caz;
    float axx=by*cz-bz*cy, ayy=bz*cx-bx*cz, azz=bx*cy-by*cx;
    vx[6]=-0.58273431f*axx+0.56802827f*bx-0.54067466f*cx;
    vy[6]=-0.58273431f*ayy+0.56802827f*by-0.54067466f*cy;
    vz[6]=-0.58273431f*azz+0.56802827f*bz-0.54067466f*cz;
  }
  float cD[3], sD[3];
  for(int t=0;t<3;t++){
    cD[t]=1.0f; sD[t]=0.0f;
    int f=3*n+t-1;
    if(f>=0 && f<3*NRES-3){
      float X[4][3];
      for(int q=0;q<4;q++){
        int m=f+q, rr=m/3, aa=m-rr*3;
        X[q][0]=bb[rr*12+aa*3]; X[q][1]=bb[rr*12+aa*3+1]; X[q][2]=bb[rr*12+aa*3+2];
      }
      float u2x=X[1][0]-X[0][0], u2y=X[1][1]-X[0][1], u2z=X[1][2]-X[0][2];
      float u1x=X[2][0]-X[1][0], u1y=X[2][1]-X[1][1], u1z=X[2][2]-X[1][2];
      float u0x=X[3][0]-X[2][0], u0y=X[3][1]-X[2][1], u0z=X[3][2]-X[2][2];
      float s2=rsqrtf(u2x*u2x+u2y*u2y+u2z*u2z+1e-8f); u2x*=s2; u2y*=s2; u2z*=s2;
      float s1=rsqrtf(u1x*u1x+u1y*u1y+u1z*u1z+1e-8f); u1x*=s1; u1y*=s1; u1z*=s1;
      float s0=rsqrtf(u0x*u0x+u0y*u0y+u0z*u0z+1e-8f); u0x*=s0; u0y*=s0; u0z*=s0;
      float n2x=u2y*u1z-u2z*u1y, n2y=u2z*u1x-u2x*u1z, n2z=u2x*u1y-u2y*u1x;
      float nn2=rsqrtf(n2x*n2x+n2y*n2y+n2z*n2z+1e-8f); n2x*=nn2; n2y*=nn2; n2z*=nn2;
      float n1x=u1y*u0z-u1z*u0y, n1y=u1z*u0x-u1x*u0z, n1z=u1x*u0y-u1y*u0x;
      float nn1=rsqrtf(n1x*n1x+n1y*n1y+n1z*n1z+1e-8f); n1x*=nn1; n1y*=nn1; n1z*=nn1;
      float dotn = n2x*n1x+n2y*n1y+n2z*n1z;
      float cosD = fminf(fmaxf(dotn, -1.0f+1e-6f), 1.0f-1e-6f);
      float sg = u2x*n1x+u2y*n1y+u2z*n1z;
      if(sg==0.0f){ cD[t]=1.0f; sD[t]=0.0f; }
      else {
        float sgn = (sg>0.0f)?1.0f:-1.0f;
        cD[t]=cosD;
        sD[t]=sgn*sqrtf(fmaxf(1.0f-cosD*cosD,0.0f));
      }
    }
  }
  float* o = bbf + n*28;
  o[0]=cD[0]; o[1]=cD[1]; o[2]=cD[2]; o[3]=sD[0]; o[4]=sD[1]; o[5]=sD[2]; o[6]=0.f;
  for(int c=0;c<7;c++){ o[7+c]=vx[c]; o[14+c]=vy[c]; o[21+c]=vz[c]; }
}

// helper: per-lane extraction of the next-smallest unconsumed value as packed u64 key.
__device__ __forceinline__ unsigned long long knn_extract(const float* __restrict__ vals,
                                                          unsigned &mask, int lane){
  float bm=INFINITY; int ba=0;
  #pragma unroll
  for(int t=0;t<32;t++){
    if(!((mask>>t)&1u) && vals[t]<bm){ bm=vals[t]; ba=t; }
  }
  mask |= 1u<<ba;
  unsigned ub = __float_as_uint(bm);
  ub ^= (ub & 0x80000000u) ? 0xFFFFFFFFu : 0x80000000u;
  return ((unsigned long long)ub<<32) | (unsigned)(ba*64+lane);
}

// ---------------- K1: kNN — wave/query, u64-key tournament with per-lane cached top-4 ----------------
__global__ __launch_bounds__(256) void k_knn(const float4* __restrict__ ca, int* __restrict__ nbr){
  __shared__ float sx[NPER], sy[NPER], sz[NPER], sq[NPER];
  int wave = threadIdx.x>>6;
  int lane = threadIdx.x&63;
  int i = blockIdx.x*4 + wave;
  int batch = i / NPER;
  int base = batch*NPER;
  for(int t=threadIdx.x; t<NPER; t+=256){
    float4 c = ca[base+t];
    sx[t]=c.x; sy[t]=c.y; sz[t]=c.z; sq[t]=c.w;
  }
  __syncthreads();
  int il = i - base;
  float xi=sx[il], yi=sy[il], zi=sz[il], si=sq[il];
  float vals[32];
  #pragma unroll
  for(int t=0;t<32;t++){
    int j = t*64 + lane;
    float d2 = si + sq[j] - 2.0f*(xi*sx[j]+yi*sy[j]+zi*sz[j]);
    if(j==il) d2 = 1e30f;
    vals[t]=d2;
  }
  unsigned mask = 0;
  unsigned long long s0 = knn_extract(vals, mask, lane);
  unsigned long long s1 = knn_extract(vals, mask, lane);
  unsigned long long s2 = knn_extract(vals, mask, lane);
  unsigned long long s3 = knn_extract(vals, mask, lane);
  const unsigned long long EMPTY = ~0ull;
  for(int it=0; it<KNB; it++){
    unsigned long long m = s0;
    #pragma unroll
    for(int off=32; off>0; off>>=1){
      unsigned long long o = __shfl_xor(m, off, 64);
      m = (o<m) ? o : m;
    }
    if(lane==0) nbr[i*KNB+it] = base + (int)(m & 0x7FFull);
    if((int)(m & 63ull) == lane){
      s0=s1; s1=s2; s2=s3; s3=EMPTY;
      if(s0==EMPTY) s0 = knn_extract(vals, mask, lane);  // rare refill
    }
  }
}

// ---------------- K2a: trig table for positional embedding ----------------
__global__ void k_tbl(float* __restrict__ tbl){
  int i = blockIdx.x*256 + threadIdx.x;   // 4096*8 items
  int d = i>>3, m = i&7;
  float freq = __expf(-1.1512925465f*(float)m);  // 10000^(-m/8)
  float ang = (float)(d-2048)*freq;
  tbl[d*16+m]   = cosf(ang);
  tbl[d*16+8+m] = sinf(ang);
}

// ---------------- K2: edge features ef (N,k,32) = [rbf16, cos8, sin8] ----------------
__global__ void k_edgefeat(const float4* __restrict__ ca, const int* __restrict__ nbr,
                           const float* __restrict__ tbl, float* __restrict__ ef){
  int e = blockIdx.x*256 + threadIdx.x;
  if(e >= NEDGE) return;
  int n = e/KNB;
  int j = nbr[e];
  float4 cn = ca[n], cj = ca[j];
  float dx=cn.x-cj.x, dy=cn.y-cj.y, dz=cn.z-cj.z;
  float dist = sqrtf(dx*dx+dy*dy+dz*dz + 1e-12f);
  float f[32];
  #pragma unroll
  for(int m=0;m<16;m++){
    float mu = (20.0f/15.0f)*(float)m;
    float t = (dist-mu)*(1.0f/1.25f);
    f[m] = __expf(-t*t);
  }
  {
    const float4* t4 = (const float4*)(tbl + (size_t)(j - n + 2048)*16);
    float4 c0=t4[0], c1=t4[1], s0=t4[2], s1=t4[3];
    f[16]=c0.x; f[17]=c0.y; f[18]=c0.z; f[19]=c0.w;
    f[20]=c1.x; f[21]=c1.y; f[22]=c1.z; f[23]=c1.w;
    f[24]=s0.x; f[25]=s0.y; f[26]=s0.z; f[27]=s0.w;
    f[28]=s1.x; f[29]=s1.y; f[30]=s1.z; f[31]=s1.w;
  }
  float4* o4 = (float4*)(ef + (size_t)e*32);
  #pragma unroll
  for(int q=0;q<8;q++) o4[q] = make_float4(f[q*4],f[q*4+1],f[q*4+2],f[q*4+3]);
}

// ---------------- K3: norm_so3 (latent only) ----------------
__global__ void k_norm(const float* __restrict__ in, float* __restrict__ out,
                       const float* __restrict__ g0, const float* __restrict__ b0,
                       const float* __restrict__ g1){
  int tid = blockIdx.x*256 + threadIdx.x;
  int n = tid >> 5, lane = tid & 31;
  if(n >= NRES) return;
  const float* xn = in + n*128;
  float x0 = xn[lane];
  float s = x0, s2 = x0*x0;
  for(int off=16; off>0; off>>=1){ s += __shfl_xor(s, off, 32); s2 += __shfl_xor(s2, off, 32); }
  float mu = s*(1.0f/32.0f);
  float var = s2*(1.0f/32.0f) - mu*mu;
  float y0 = (x0-mu)*rsqrtf(var+1e-6f)*g0[lane] + b0[lane];
  float v1 = xn[32+lane], v2 = xn[64+lane], v3 = xn[96+lane];
  float ss = v1*v1+v2*v2+v3*v3;
  for(int off=16; off>0; off>>=1){ ss += __shfl_xor(ss, off, 32); }
  float sc = rsqrtf(ss*(1.0f/96.0f) + 1e-6f);
  float g = g1[lane];
  out[n*128+lane]     = y0;
  out[n*128+32+lane]  = v1*sc*g;
  out[n*128+64+lane]  = v2*sc*g;
  out[n*128+96+lane]  = v3*sc*g;
}

// helper: load 32 floats into a register array (callers index with constants only)
__device__ __forceinline__ void load32(float* __restrict__ f, const float* __restrict__ src){
  const float4* s4 = (const float4*)src;
  #pragma unroll
  for(int q=0;q<8;q++){
    float4 v = s4[q];
    f[q*4+0]=v.x; f[q*4+1]=v.y; f[q*4+2]=v.z; f[q*4+3]=v.w;
  }
}

// ---------------- K4a: init radial MLPs, lane-per-edge, v2f packed FMA ----------------
__global__ __launch_bounds__(128, 4)
void k_rad(const float* __restrict__ ef,
           const float* __restrict__ bbw1, const float* __restrict__ bbw2,
           const float* __restrict__ latw1, const float* __restrict__ latw2,
           float* __restrict__ radbb, float* __restrict__ radlat){
  int e = blockIdx.x*128 + threadIdx.x;
  float f[32];
  load32(f, ef + (size_t)e*32);
  // ---- bb branch: 32->64(silu)->7, o in two halves of 32 (same FP order) ----
  float ab[7];
  #pragma unroll
  for(int t=0;t<7;t++) ab[t]=0.f;
  #pragma unroll
  for(int half=0; half<2; half++){
    v2f h[16];
    #pragma unroll
    for(int o=0;o<16;o++) h[o]=splat2(0.f);
    #pragma unroll
    for(int c=0;c<32;c++){
      v2f fc = splat2(f[c]);
      const v2f* w = (const v2f*)(bbw1 + c*64 + half*32);
      #pragma unroll
      for(int o=0;o<16;o++) h[o] += fc*w[o];
    }
    #pragma unroll
    for(int o=0;o<16;o++){
      float v0 = siluf(h[o].x), v1 = siluf(h[o].y);
      const float* wa = bbw2 + (half*32+o*2)*7;
      const float* wb = bbw2 + (half*32+o*2+1)*7;
      #pragma unroll
      for(int t=0;t<7;t++) ab[t] += v0*wa[t];
      #pragma unroll
      for(int t=0;t<7;t++) ab[t] += v1*wb[t];
    }
  }
  {
    float4* rb4 = (float4*)(radbb + (size_t)e*8);
    rb4[0] = make_float4(ab[0],ab[1],ab[2],ab[3]);
    rb4[1] = make_float4(ab[4],ab[5],ab[6],0.f);
  }
  // ---- lat branch: 32->64(silu)->32, o-halved, v2f ----
  v2f al[16];
  #pragma unroll
  for(int t=0;t<16;t++) al[t]=splat2(0.f);
  #pragma unroll
  for(int half=0; half<2; half++){
    v2f h[16];
    #pragma unroll
    for(int o=0;o<16;o++) h[o]=splat2(0.f);
    #pragma unroll
    for(int c=0;c<32;c++){
      v2f fc = splat2(f[c]);
      const v2f* w = (const v2f*)(latw1 + c*64 + half*32);
      #pragma unroll
      for(int o=0;o<16;o++) h[o] += fc*w[o];
    }
    #pragma unroll
    for(int o=0;o<16;o++){
      float v0 = siluf(h[o].x), v1 = siluf(h[o].y);
      const v2f* wa = (const v2f*)(latw2 + (half*32+o*2)*32);
      const v2f* wb = (const v2f*)(latw2 + (half*32+o*2+1)*32);
      v2f va = splat2(v0), vb = splat2(v1);
      #pragma unroll
      for(int t=0;t<16;t++) al[t] += va*wa[t];
      #pragma unroll
      for(int t=0;t<16;t++) al[t] += vb*wb[t];
    }
  }
  v2f* rl2 = (v2f*)(radlat + (size_t)e*32);
  #pragma unroll
  for(int q=0;q<16;q++) rl2[q] = al[q];
}

// ---------------- K4: init gather + out-proj + fused norm (wave/node) ----------------
__global__ __launch_bounds__(256) void k_init(const int* __restrict__ nbr,
                       const float* __restrict__ radbb, const float* __restrict__ radlat,
                       const float* __restrict__ bbf, const float* __restrict__ latn,
                       const float* __restrict__ bboutw, const float* __restrict__ latoutw,
                       const float* __restrict__ g0, const float* __restrict__ b0,
                       const float* __restrict__ g1,
                       float* __restrict__ x, float* __restrict__ xl){
  __shared__ float msgbb[4][32], msglat[4][128], xout[4][128];
  int g = threadIdx.x>>6, t = threadIdx.x&63;
  int n = blockIdx.x*4 + g;
  int t31 = t&31, t7 = t%7;
  float accL0=0.f, accL1=0.f, accB=0.f;
  for(int kk=0; kk<KNB; kk++){
    int e = n*KNB+kk;
    int j = nbr[e];
    float rl = radlat[(size_t)e*32 + t31];
    accL0 += latn[j*128+t]    * rl;
    accL1 += latn[j*128+64+t] * rl;
    if(t<28) accB += bbf[j*28+t]*radbb[(size_t)e*8 + t7];
  }
  msglat[g][t]=accL0*(1.0f/KNB); msglat[g][64+t]=accL1*(1.0f/KNB);
  if(t<28) msgbb[g][t]=accB*(1.0f/KNB);
  for(int half=0; half<2; half++){
    int e = half*64+t;
    int rrow = e>>5, c = e&31;
    float v=0.f;
    if(c<16){ for(int q=0;q<7;q++)  v += msgbb[g][rrow*7+q]*bboutw[q*16+c]; }
    else    { for(int q=0;q<32;q++) v += msglat[g][rrow*32+q]*latoutw[q*16+(c-16)]; }
    xout[g][e]=v;
    x[n*128+e]=v;
  }
  if(t<32){
    float x0=xout[g][t];
    float s=x0, s2=x0*x0;
    for(int off=16; off>0; off>>=1){ s+=__shfl_xor(s,off,32); s2+=__shfl_xor(s2,off,32); }
    float mu=s*(1.0f/32.0f), var=s2*(1.0f/32.0f)-mu*mu;
    float y0=(x0-mu)*rsqrtf(var+1e-6f)*g0[t]+b0[t];
    float v1=xout[g][32+t], v2=xout[g][64+t], v3=xout[g][96+t];
    float ss=v1*v1+v2*v2+v3*v3;
    for(int off=16; off>0; off>>=1) ss+=__shfl_xor(ss,off,32);
    float sc=rsqrtf(ss*(1.0f/96.0f)+1e-6f);
    float gg=g1[t];
    xl[n*128+t]=y0; xl[n*128+32+t]=v1*sc*gg; xl[n*128+64+t]=v2*sc*gg; xl[n*128+96+t]=v3*sc*gg;
  }
}

// ---------------- K4b: per-node hoisted halves of edge-MLP + attn-logit MLP ----------------
__global__ __launch_bounds__(256) void k_nodeprep(const float* __restrict__ x,
                       const float* __restrict__ xl,
                       const float* __restrict__ ew1, const float* __restrict__ aw1,
                       float* __restrict__ hsrc, float* __restrict__ hdst,
                       float* __restrict__ asrc, float* __restrict__ adst){
  __shared__ float sx[4][32], sl[4][32];
  int g = threadIdx.x>>6, lane = threadIdx.x&63;
  int n = blockIdx.x*4 + g;
  if(lane<32){
    if(x)   sx[g][lane] = x[n*128+lane];
    if(aw1) sl[g][lane] = xl[n*128+lane];
  }
  __syncthreads();
  if(x){
    float a0=0.f, a1=0.f;
    #pragma unroll
    for(int c=0;c<32;c++){
      float xv = sx[g][c];
      a0 += xv*ew1[(32+c)*64+lane];
      a1 += xv*ew1[(64+c)*64+lane];
    }
    hsrc[n*64+lane]=a0; hdst[n*64+lane]=a1;
  }
  if(aw1){
    int o = lane&31;
    int roff = (lane>=32)? 32 : 0;
    float a=0.f;
    #pragma unroll
    for(int c=0;c<32;c++) a += sl[g][c]*aw1[(roff+c)*32+o];
    if(lane<32) asrc[n*32+o]=a; else adst[n*32+o]=a;
  }
}

// ---------------- K5: attention logits (standalone, layer 0 only; v2f packed) ----------------
__global__ __launch_bounds__(128, 4)
void k_logits(const int* __restrict__ nbr,
              const float* __restrict__ asrc, const float* __restrict__ adst,
              const float* __restrict__ ef, const float* __restrict__ w1,
              const float* __restrict__ w2, float* __restrict__ logits){
  int e = blockIdx.x*128 + threadIdx.x;
  int n = e/KNB;
  int j = nbr[e];
  v2f h[16];
  {
    const v2f* pj = (const v2f*)(asrc + (size_t)j*32);
    const v2f* pn = (const v2f*)(adst + (size_t)n*32);
    #pragma unroll
    for(int q=0;q<16;q++) h[q] = pj[q]+pn[q];
  }
  float f[32];
  load32(f, ef + (size_t)e*32);
  #pragma unroll
  for(int c=0;c<32;c++){
    v2f fc = splat2(f[c]);
    const v2f* w = (const v2f*)(w1 + (64+c)*32);
    #pragma unroll
    for(int o=0;o<16;o++) h[o] += fc*w[o];
  }
  v2f acc[4];
  #pragma unroll
  for(int t=0;t<4;t++) acc[t]=splat2(0.f);
  #pragma unroll
  for(int o=0;o<16;o++){
    float v0 = siluf(h[o].x), v1 = siluf(h[o].y);
    const v2f* wa = (const v2f*)(w2 + (o*2)*8);
    const v2f* wb = (const v2f*)(w2 + (o*2+1)*8);
    v2f va = splat2(v0), vb = splat2(v1);
    #pragma unroll
    for(int t=0;t<4;t++) acc[t] += va*wa[t];
    #pragma unroll
    for(int t=0;t<4;t++) acc[t] += vb*wb[t];
  }
  v2f* lg2 = (v2f*)(logits + (size_t)e*8);
  #pragma unroll
  for(int q=0;q<4;q++) lg2[q] = acc[q];
}

// ---------------- K7: softmax + aggregate + o_w + FFN + fused norm (v2f packed hot loops) ----------------
__global__ __launch_bounds__(256) void k_update(const int* __restrict__ nbr, const float* __restrict__ xl,
                         const float* __restrict__ logits, float* __restrict__ x,
                         float* __restrict__ xlout,
                         const float* __restrict__ vw, const float* __restrict__ ow,
                         const float* __restrict__ fw1, const float* __restrict__ fw2,
                         const float* __restrict__ fwg, const float* __restrict__ fv1,
                         const float* __restrict__ g0, const float* __restrict__ b0,
                         const float* __restrict__ g1){
  __shared__ float S_lg[4][240], S_m[4][8], S_inv[4][8];
  __shared__ float S_S[4][1024], S_agg[4][512], S_x[4][128];
  __shared__ float S_h[4][64], S_g[4][32], S_d0[4][32];
  int g = threadIdx.x>>6, t = threadIdx.x&63;
  int n = blockIdx.x*4 + g;
  for(int r=t; r<240; r+=64) S_lg[g][r] = logits[(size_t)n*240+r];
  if(t<8){
    float m=-1e30f;
    for(int kk=0;kk<KNB;kk++) m=fmaxf(m, S_lg[g][kk*8+t]);
    float s=0.f;
    for(int kk=0;kk<KNB;kk++) s += __expf(S_lg[g][kk*8+t]-m);
    S_m[g][t]=m; S_inv[g][t]=1.0f/s;
  }
  for(int r=t; r<240; r+=64){ int h=r&7; S_lg[g][r]=__expf(S_lg[g][r]-S_m[g][h])*S_inv[g][h]; }
  int hd = t>>3, i8 = t&7;
  v2f acc[8];
  #pragma unroll
  for(int m=0;m<8;m++) acc[m]=splat2(0.f);
  for(int kk=0;kk<KNB;kk++){
    int j=nbr[n*KNB+kk];
    v2f a = splat2(S_lg[g][kk*8+hd]);
    const v2f* xr = (const v2f*)(xl + (size_t)j*128 + i8*16);
    #pragma unroll
    for(int q=0;q<8;q++) acc[q] += a*xr[q];
  }
  #pragma unroll
  for(int q=0;q<8;q++){ S_S[g][hd*128 + i8*16 + 2*q] = acc[q].x; S_S[g][hd*128 + i8*16 + 2*q+1] = acc[q].y; }
  __syncthreads();
  for(int half=0; half<2; half++){
    int hv = half*64+t;
    int hh = hv>>4;
    v2f a01=splat2(0.f), a23=splat2(0.f);
    for(int c=0;c<32;c++){
      v2f w = splat2(vw[c*128+hv]);
      v2f s01; s01.x = S_S[g][hh*128 + c];      s01.y = S_S[g][hh*128 + 32+c];
      v2f s23; s23.x = S_S[g][hh*128 + 64+c];   s23.y = S_S[g][hh*128 + 96+c];
      a01 += s01*w; a23 += s23*w;
    }
    S_agg[g][hv]=a01.x; S_agg[g][128+hv]=a01.y; S_agg[g][256+hv]=a23.x; S_agg[g][384+hv]=a23.y;
  }
  __syncthreads();
  {
    int c = t&31, r0 = t>>5;
    v2f v01; v01.x = x[n*128+t]; v01.y = x[n*128+64+t];
    for(int hv=0;hv<128;hv++){
      v2f s; s.x = S_agg[g][r0*128+hv]; s.y = S_agg[g][(r0+2)*128+hv];
      v01 += s*splat2(ow[hv*32+c]);
    }
    S_x[g][t]=v01.x; S_x[g][64+t]=v01.y;
  }
  __syncthreads();
  {
    float hs=0.f;
    for(int c=0;c<32;c++) hs += S_x[g][c]*fw1[c*64+t];
    S_h[g][t]=siluf(hs);
  }
  __syncthreads();
  if(t<32){
    float gs=0.f, d0=0.f;
    for(int c=0;c<64;c++){ float hv=S_h[g][c]; gs += hv*fwg[c*32+t]; d0 += hv*fw2[c*32+t]; }
    S_g[g][t]=1.0f/(1.0f+__expf(-gs));
    S_d0[g][t]=d0;
  }
  __syncthreads();
  for(int half=0; half<2; half++){
    int e = half*64+t;
    int rrow = e>>5, c = e&31;
    float xv = S_x[g][e], outv;
    if(rrow==0){ outv = xv + S_d0[g][c]; }
    else {
      float dv=0.f;
      for(int cc=0;cc<32;cc++) dv += S_x[g][rrow*32+cc]*fv1[cc*32+c];
      outv = xv + dv*S_g[g][c];
    }
    __syncthreads();
    S_x[g][e]=outv;
    x[n*128+e]=outv;
  }
  __syncthreads();
  if(t<32){
    float x0=S_x[g][t];
    float s=x0, s2=x0*x0;
    for(int off=16; off>0; off>>=1){ s+=__shfl_xor(s,off,32); s2+=__shfl_xor(s2,off,32); }
    float mu=s*(1.0f/32.0f), var=s2*(1.0f/32.0f)-mu*mu;
    float y0=(x0-mu)*rsqrtf(var+1e-6f)*g0[t]+b0[t];
    float v1=S_x[g][32+t], v2=S_x[g][64+t], v3=S_x[g][96+t];
    float ss=v1*v1+v2*v2+v3*v3;
    for(int off=16; off>0; off>>=1) ss+=__shfl_xor(ss,off,32);
    float sc=rsqrtf(ss*(1.0f/96.0f)+1e-6f);
    float gg=g1[t];
    xlout[n*128+t]=y0; xlout[n*128+32+t]=v1*sc*gg;
    xlout[n*128+64+t]=v2*sc*gg; xlout[n*128+96+t]=v3*sc*gg;
  }
}

// ---------------- K8: edge update + (optional) next-layer logits; QUAD-SPLIT (4 lanes/edge) ----------------
// Lane p of each quad owns: h-slice o in [p*16,p*16+16), output/t-slice [p*8,p*8+8),
// h2-slice [p*8,p*8+8), logit-slice [p*2,p*2+2). All sums ascending -> bit-identical.
template<bool FUSE_LOGITS>
__global__ __launch_bounds__(256, 4)
void k_efup_q(const int* __restrict__ nbr,
              const float* __restrict__ hsrc, const float* __restrict__ hdst,
              const float* __restrict__ ew1, const float* __restrict__ ew2,
              float* __restrict__ ef,
              const float* __restrict__ asrc, const float* __restrict__ adst,
              const float* __restrict__ aw1n, const float* __restrict__ aw2n,
              float* __restrict__ logits){
  int tid = blockIdx.x*256 + threadIdx.x;
  int e = tid>>2, p = tid&3;
  int n = e/KNB;
  int j = nbr[e];
  // f slice: f[p*8 .. p*8+8)
  float fs[8];
  {
    const float4* s4 = (const float4*)(ef + (size_t)e*32 + p*8);
    float4 a=s4[0], b=s4[1];
    fs[0]=a.x; fs[1]=a.y; fs[2]=a.z; fs[3]=a.w; fs[4]=b.x; fs[5]=b.y; fs[6]=b.z; fs[7]=b.w;
  }
  // h slice (16 wide)
  v2f h[8];
  {
    const float4* pj = (const float4*)(hsrc + (size_t)j*64 + p*16);
    const float4* pn = (const float4*)(hdst + (size_t)n*64 + p*16);
    #pragma unroll
    for(int q=0;q<4;q++){
      float4 a=pj[q], b=pn[q];
      h[2*q]   = (v2f){a.x+b.x, a.y+b.y};
      h[2*q+1] = (v2f){a.z+b.z, a.w+b.w};
    }
  }
  // h[o] += f[c]*ew1[c][o-slice], c = CQ*8+i ascending 0..31
  #define EW1_BLK(CQ) \
    { _Pragma("unroll") \
      for(int i=0;i<8;i++){ \
        v2f fc = splat2(qb<CQ>(fs[i])); \
        const v2f* w = (const v2f*)(ew1 + (CQ*8+i)*64 + p*16); \
        _Pragma("unroll") \
        for(int o=0;o<8;o++) h[o] += fc*w[o]; \
      } }
  EW1_BLK(0) EW1_BLK(1) EW1_BLK(2) EW1_BLK(3)
  #undef EW1_BLK
  // silu
  float s[16];
  #pragma unroll
  for(int o=0;o<8;o++){ s[2*o]=siluf(h[o].x); s[2*o+1]=siluf(h[o].y); }
  // acc[t-slice] += silu(h[o])*ew2[o][t-slice], o = OQ*16+i ascending 0..63
  v2f acc[4];
  #pragma unroll
  for(int t=0;t<4;t++) acc[t]=splat2(0.f);
  #define EW2_BLK(OQ) \
    { _Pragma("unroll") \
      for(int i=0;i<16;i++){ \
        v2f sv = splat2(qb<OQ>(s[i])); \
        const v2f* w = (const v2f*)(ew2 + (OQ*16+i)*32 + p*8); \
        _Pragma("unroll") \
        for(int t=0;t<4;t++) acc[t] += sv*w[t]; \
      } }
  EW2_BLK(0) EW2_BLK(1) EW2_BLK(2) EW2_BLK(3)
  #undef EW2_BLK
  // residual: new ef slice
  #pragma unroll
  for(int t=0;t<4;t++){ fs[2*t] += acc[t].x; fs[2*t+1] += acc[t].y; }
  {
    float4* o4 = (float4*)(ef + (size_t)e*32 + p*8);
    o4[0] = make_float4(fs[0],fs[1],fs[2],fs[3]);
    o4[1] = make_float4(fs[4],fs[5],fs[6],fs[7]);
  }
  if(FUSE_LOGITS){
    // h2 slice (8 wide)
    v2f h2[4];
    {
      const float4* pj = (const float4*)(asrc + (size_t)j*32 + p*8);
      const float4* pn = (const float4*)(adst + (size_t)n*32 + p*8);
      #pragma unroll
      for(int q=0;q<2;q++){
        float4 a=pj[q], b=pn[q];
        h2[2*q]   = (v2f){a.x+b.x, a.y+b.y};
        h2[2*q+1] = (v2f){a.z+b.z, a.w+b.w};
      }
    }
    // h2[o] += newf[c]*aw1n[(64+c)][o-slice], c ascending 0..31
    #define AW1_BLK(CQ) \
      { _Pragma("unroll") \
        for(int i=0;i<8;i++){ \
          v2f fc = splat2(qb<CQ>(fs[i])); \
          const v2f* w = (const v2f*)(aw1n + (64+CQ*8+i)*32 + p*8); \
          _Pragma("unroll") \
          for(int o=0;o<4;o++) h2[o] += fc*w[o]; \
        } }
    AW1_BLK(0) AW1_BLK(1) AW1_BLK(2) AW1_BLK(3)
    #undef AW1_BLK
    float s2[8];
    #pragma unroll
    for(int o=0;o<4;o++){ s2[2*o]=siluf(h2[o].x); s2[2*o+1]=siluf(h2[o].y); }
    // a8[t-slice] += silu(h2[o])*aw2n[o][t-slice], o ascending 0..31
    v2f a8 = splat2(0.f);
    #define AW2_BLK(OQ) \
      { _Pragma("unroll") \
        for(int i=0;i<8;i++){ \
          v2f sv = splat2(qb<OQ>(s2[i])); \
          const v2f* w = (const v2f*)(aw2n + (OQ*8+i)*8 + p*2); \
          a8 += sv*w[0]; \
        } }
    AW2_BLK(0) AW2_BLK(1) AW2_BLK(2) AW2_BLK(3)
    #undef AW2_BLK
    *(v2f*)(logits + (size_t)e*8 + p*2) = a8;
  }
}

// ---------------- K9a: out radial MLP, lane-per-edge, v2f packed -> orad (E,32) ----------------
__global__ __launch_bounds__(128, 4)
void k_orad(const float* __restrict__ ef,
            const float* __restrict__ orw1, const float* __restrict__ orw2,
            float* __restrict__ orad){
  int e = blockIdx.x*128 + threadIdx.x;
  float f[32];
  load32(f, ef + (size_t)e*32);
  v2f acc[16];
  #pragma unroll
  for(int t=0;t<16;t++) acc[t]=splat2(0.f);
  #pragma unroll
  for(int half=0; half<2; half++){
    v2f h[16];
    #pragma unroll
    for(int o=0;o<16;o++) h[o]=splat2(0.f);
    #pragma unroll
    for(int c=0;c<32;c++){
      v2f fc = splat2(f[c]);
      const v2f* w = (const v2f*)(orw1 + c*64 + half*32);
      #pragma unroll
      for(int o=0;o<16;o++) h[o] += fc*w[o];
    }
    #pragma unroll
    for(int o=0;o<16;o++){
      float v0 = siluf(h[o].x), v1 = siluf(h[o].y);
      const v2f* wa = (const v2f*)(orw2 + (half*32+o*2)*32);
      const v2f* wb = (const v2f*)(orw2 + (half*32+o*2+1)*32);
      v2f va = splat2(v0), vb = splat2(v1);
      #pragma unroll
      for(int t=0;t<16;t++) acc[t] += va*wa[t];
      #pragma unroll
      for(int t=0;t<16;t++) acc[t] += vb*wb[t];
    }
  }
  v2f* r2 = (v2f*)(orad + (size_t)e*32);
  #pragma unroll
  for(int q=0;q<16;q++) r2[q] = acc[q];
}

// ---------------- K9: out gather + projection + fused seq head ----------------
__global__ __launch_bounds__(256) void k_out(const int* __restrict__ nbr, const float* __restrict__ orad,
                      const float* __restrict__ x,
                      const float* __restrict__ outw,
                      const float* __restrict__ sw1, const float* __restrict__ sb1,
                      const float* __restrict__ sw2, const float* __restrict__ sb2,
                      const float* __restrict__ sw3, const float* __restrict__ sb3,
                      float* __restrict__ out, float* __restrict__ outseq){
  __shared__ float msg[4][128];
  __shared__ float h1[4][64], h2[4][32], lgs[4][20];
  int g = threadIdx.x>>6, t = threadIdx.x&63;
  int n = blockIdx.x*4 + g;
  int t31 = t&31;
  float acc0=0.f, acc1=0.f;
  for(int kk=0;kk<KNB;kk++){
    int e=n*KNB+kk;
    int j=nbr[e];
    float rl = orad[(size_t)e*32 + t31];
    acc0 += x[j*128+t]*rl;
    acc1 += x[j*128+64+t]*rl;
  }
  msg[g][t]=acc0*(1.0f/KNB); msg[g][64+t]=acc1*(1.0f/KNB);
  for(int o=t;o<91;o+=64){
    for(int rrow=1;rrow<4;rrow++){
      float s=0.f;
      for(int c=0;c<32;c++) s += msg[g][rrow*32+c]*outw[c*91+o];
      out[(size_t)n*273 + o*3 + (rrow-1)] = s;
    }
  }
  {
    float s=0.f;
    for(int c=0;c<32;c++) s += x[n*128+c]*sw1[c*64+t];
    h1[g][t]=fmaxf(s+sb1[t],0.f);
  }
  if(t<32){
    float s=0.f;
    for(int c=0;c<64;c++) s += h1[g][c]*sw2[c*32+t];
    h2[g][t]=fmaxf(s+sb2[t],0.f);
  }
  if(t<20){
    float s=0.f;
    for(int c=0;c<32;c++) s += h2[g][c]*sw3[c*20+t];
    lgs[g][t]=s+sb3[t];
  }
  if(t<20){
    float m=-1e30f;
    for(int c=0;c<20;c++) m=fmaxf(m,lgs[g][c]);
    float se=0.f;
    for(int c=0;c<20;c++) se += __expf(lgs[g][c]-m);
    outseq[(size_t)n*20+t]=lgs[g][t]-m-logf(se);
  }
}

extern "C" void kernel_launch(void* const* d_in, const int* in_sizes, int n_in,
                              void* d_out, int out_size, void* d_ws, size_t ws_size,
                              hipStream_t stream) {
  const float* bb      = (const float*)d_in[0];
  const float* latent  = (const float*)d_in[1];
  const float* ln_g0   = (const float*)d_in[2];
  const float* ln_b0   = (const float*)d_in[3];
  const float* ln_g1   = (const float*)d_in[4];
  const float* bbw1    = (const float*)d_in[5];
  const float* bbw2    = (const float*)d_in[6];
  const float* bboutw  = (const float*)d_in[7];
  const float* latw1   = (const float*)d_in[8];
  const float* latw2   = (const float*)d_in[9];
  const float* latoutw = (const float*)d_in[10];
  const float* tg0     = (const float*)d_in[11];
  const float* tb0     = (const float*)d_in[12];
  const float* tg1     = (const float*)d_in[13];
  const float* aw1     = (const float*)d_in[14];
  const float* aw2     = (const float*)d_in[15];
  const float* vw      = (const float*)d_in[16];
  const float* ow      = (const float*)d_in[17];
  const float* fw1     = (const float*)d_in[18];
  const float* fw2     = (const float*)d_in[19];
  const float* fwg     = (const float*)d_in[20];
  const float* fv1     = (const float*)d_in[21];
  const float* ew1     = (const float*)d_in[22];
  const float* ew2     = (const float*)d_in[23];
  const float* orw1    = (const float*)d_in[24];
  const float* orw2    = (const float*)d_in[25];
  const float* outw    = (const float*)d_in[26];
  const float* sw1     = (const float*)d_in[27];
  const float* sb1     = (const float*)d_in[28];
  const float* sw2     = (const float*)d_in[29];
  const float* sb2     = (const float*)d_in[30];
  const float* sw3     = (const float*)d_in[31];
  const float* sb3     = (const float*)d_in[32];
  float* outp = (float*)d_out;

  // workspace layout (radbb overlays logits; tbl/radlat/orad + nodeprep overlay edgescratch)
  int*    nbr    = (int*)d_ws;
  float*  ef     = (float*)((char*)d_ws + 1024*1024);
  float*  xbuf   = ef   + (size_t)NEDGE*32;
  float*  xlA    = xbuf + (size_t)NRES*128;
  float*  xlB    = xlA  + (size_t)NRES*128;
  float*  bbf    = xlB  + (size_t)NRES*128;
  float*  logits = bbf  + (size_t)NRES*28;
  float4* ca     = (float4*)(logits + (size_t)NEDGE*8);
  float*  edgescratch = (float*)(ca + NRES);     // NEDGE*32 floats
  float*  radbb  = logits;                       // NEDGE*8, dead before first k_logits
  float*  radlat = edgescratch;                  // NEDGE*32, dead after k_init
  float*  orad   = edgescratch;                  // reused at the end
  float*  tbl    = edgescratch;                  // 4096*16 floats, dead before k_rad writes radlat
  // per-node hoisted arrays: live only between k_init and k_orad (radlat dead window)
  float*  hsrc   = edgescratch;                              // NRES*64
  float*  hdst   = edgescratch + (size_t)NRES*64;            // NRES*64
  float*  asrc   = edgescratch + (size_t)NRES*128;           // NRES*32
  float*  adst   = edgescratch + (size_t)NRES*128 + (size_t)NRES*32; // NRES*32

  k_bbfeat  <<<NRES/256, 256, 0, stream>>>(bb, bbf, ca);
  k_knn     <<<NRES/4,   256, 0, stream>>>(ca, nbr);
  k_tbl     <<<4096*8/256, 256, 0, stream>>>(tbl);
  k_edgefeat<<<NEDGE/256, 256, 0, stream>>>(ca, nbr, tbl, ef);
  k_norm    <<<NRES*32/256, 256, 0, stream>>>(latent, xlA, ln_g0, ln_b0, ln_g1);
  k_rad     <<<NEDGE/128, 128, 0, stream>>>(ef, bbw1, bbw2, latw1, latw2, radbb, radlat);
  k_init    <<<NRES/4, 256, 0, stream>>>(nbr, radbb, radlat, bbf, xlA,
                                         bboutw, latoutw,
                                         tg0, tb0, tg1,
                                         xbuf, xlB);
  // layer-0 logits: hoist xl halves, then per-edge ef part
  k_nodeprep<<<NRES/4, 256, 0, stream>>>(nullptr, xlB, ew1, aw1, hsrc, hdst, asrc, adst);
  k_logits  <<<NEDGE/128, 128, 0, stream>>>(nbr, asrc, adst, ef, aw1, aw2, logits);
  for(int l=0;l<4;l++){
    const float* xl_in  = (l&1) ? xlA : xlB;
    float*       xl_out = (l&1) ? xlB : xlA;
    int ln = (l+1<4) ? (l+1) : 3;
    k_update <<<NRES/4, 256, 0, stream>>>(nbr, xl_in, logits, xbuf, xl_out,
                                          vw+l*32*128, ow+l*128*32,
                                          fw1+l*32*64, fw2+l*64*32,
                                          fwg+l*64*32, fv1+l*32*32,
                                          tg0+ln*32, tb0+ln*32, tg1+ln*32);
    if(l<3){
      k_nodeprep<<<NRES/4, 256, 0, stream>>>(xbuf, xl_out, ew1+l*96*64, aw1+(l+1)*96*32,
                                             hsrc, hdst, asrc, adst);
      k_efup_q<true><<<NEDGE/64, 256, 0, stream>>>(nbr, hsrc, hdst,
                                                   ew1+l*96*64, ew2+l*64*32, ef,
                                                   asrc, adst,
                                                   aw1+(l+1)*96*32, aw2+(l+1)*32*8, logits);
    } else {
      k_nodeprep<<<NRES/4, 256, 0, stream>>>(xbuf, xl_out, ew1+l*96*64, nullptr,
                                             hsrc, hdst, asrc, adst);
      k_efup_q<false><<<NEDGE/64, 256, 0, stream>>>(nbr, hsrc, hdst,
                                                    ew1+l*96*64, ew2+l*64*32, ef,
                                                    nullptr, nullptr,
                                                    nullptr, nullptr, nullptr);
    }
  }
  k_orad<<<NEDGE/128, 128, 0, stream>>>(ef, orw1, orw2, orad);
  k_out <<<NRES/4, 256, 0, stream>>>(nbr, orad, xbuf, outw,
                                     sw1, sb1, sw2, sb2, sw3, sb3,
                                     outp, outp + (size_t)NRES*273);
}

// Round 6
// 1210.116 us; speedup vs baseline: 1.3089x; 1.3089x over previous
//
#include <hip/hip_runtime.h>
#include <math.h>

#define NRES 8192
#define NPER 2048
#define KNB  30
#define NEDGE (NRES*KNB)

typedef float v2f __attribute__((ext_vector_type(2)));

__device__ __forceinline__ float siluf(float x){ return x / (1.0f + __expf(-x)); }
__device__ __forceinline__ v2f splat2(float a){ v2f r; r.x=a; r.y=a; return r; }

// ---------------- K0: backbone features + ca pack ----------------
__global__ void k_bbfeat(const float* __restrict__ bb, float* __restrict__ bbf,
                         float4* __restrict__ ca){
  int n = blockIdx.x*256 + threadIdx.x;
  if(n >= NRES) return;
  const float* r = bb + n*12;
  float cax=r[3], cay=r[4], caz=r[5];
  ca[n] = make_float4(cax,cay,caz, cax*cax+cay*cay+caz*caz);
  float vx[7],vy[7],vz[7];
  for(int a=0;a<4;a++){ vx[a]=r[a*3]-cax; vy[a]=r[a*3+1]-cay; vz[a]=r[a*3+2]-caz; }
  if(n<NRES-1){
    float dx=bb[(n+1)*12+3]-cax, dy=bb[(n+1)*12+4]-cay, dz=bb[(n+1)*12+5]-caz;
    float s=rsqrtf(dx*dx+dy*dy+dz*dz+1e-8f);
    vx[4]=dx*s; vy[4]=dy*s; vz[4]=dz*s;
  } else { vx[4]=0.f; vy[4]=0.f; vz[4]=0.f; }
  if(n>0){
    float dx=bb[(n-1)*12+3]-cax, dy=bb[(n-1)*12+4]-cay, dz=bb[(n-1)*12+5]-caz;
    float s=rsqrtf(dx*dx+dy*dy+dz*dz+1e-8f);
    vx[5]=dx*s; vy[5]=dy*s; vz[5]=dz*s;
  } else { vx[5]=0.f; vy[5]=0.f; vz[5]=0.f; }
  {
    float bx=cax-r[0], by=cay-r[1], bz=caz-r[2];
    float cx=r[6]-cax, cy=r[7]-cay, cz=r[8]-caz;
    float axx=by*cz-bz*cy, ayy=bz*cx-bx*cz, azz=bx*cy-by*cx;
    vx[6]=-0.58273431f*axx+0.56802827f*bx-0.54067466f*cx;
    vy[6]=-0.58273431f*ayy+0.56802827f*by-0.54067466f*cy;
    vz[6]=-0.58273431f*azz+0.56802827f*bz-0.54067466f*cz;
  }
  float cD[3], sD[3];
  for(int t=0;t<3;t++){
    cD[t]=1.0f; sD[t]=0.0f;
    int f=3*n+t-1;
    if(f>=0 && f<3*NRES-3){
      float X[4][3];
      for(int q=0;q<4;q++){
        int m=f+q, rr=m/3, aa=m-rr*3;
        X[q][0]=bb[rr*12+aa*3]; X[q][1]=bb[rr*12+aa*3+1]; X[q][2]=bb[rr*12+aa*3+2];
      }
      float u2x=X[1][0]-X[0][0], u2y=X[1][1]-X[0][1], u2z=X[1][2]-X[0][2];
      float u1x=X[2][0]-X[1][0], u1y=X[2][1]-X[1][1], u1z=X[2][2]-X[1][2];
      float u0x=X[3][0]-X[2][0], u0y=X[3][1]-X[2][1], u0z=X[3][2]-X[2][2];
      float s2=rsqrtf(u2x*u2x+u2y*u2y+u2z*u2z+1e-8f); u2x*=s2; u2y*=s2; u2z*=s2;
      float s1=rsqrtf(u1x*u1x+u1y*u1y+u1z*u1z+1e-8f); u1x*=s1; u1y*=s1; u1z*=s1;
      float s0=rsqrtf(u0x*u0x+u0y*u0y+u0z*u0z+1e-8f); u0x*=s0; u0y*=s0; u0z*=s0;
      float n2x=u2y*u1z-u2z*u1y, n2y=u2z*u1x-u2x*u1z, n2z=u2x*u1y-u2y*u1x;
      float nn2=rsqrtf(n2x*n2x+n2y*n2y+n2z*n2z+1e-8f); n2x*=nn2; n2y*=nn2; n2z*=nn2;
      float n1x=u1y*u0z-u1z*u0y, n1y=u1z*u0x-u1x*u0z, n1z=u1x*u0y-u1y*u0x;
      float nn1=rsqrtf(n1x*n1x+n1y*n1y+n1z*n1z+1e-8f); n1x*=nn1; n1y*=nn1; n1z*=nn1;
      float dotn = n2x*n1x+n2y*n1y+n2z*n1z;
      float cosD = fminf(fmaxf(dotn, -1.0f+1e-6f), 1.0f-1e-6f);
      float sg = u2x*n1x+u2y*n1y+u2z*n1z;
      if(sg==0.0f){ cD[t]=1.0f; sD[t]=0.0f; }
      else {
        float sgn = (sg>0.0f)?1.0f:-1.0f;
        cD[t]=cosD;
        sD[t]=sgn*sqrtf(fmaxf(1.0f-cosD*cosD,0.0f));
      }
    }
  }
  float* o = bbf + n*28;
  o[0]=cD[0]; o[1]=cD[1]; o[2]=cD[2]; o[3]=sD[0]; o[4]=sD[1]; o[5]=sD[2]; o[6]=0.f;
  for(int c=0;c<7;c++){ o[7+c]=vx[c]; o[14+c]=vy[c]; o[21+c]=vz[c]; }
}

// helper: per-lane extraction of the next-smallest unconsumed value as packed u64 key.
__device__ __forceinline__ unsigned long long knn_extract(const float* __restrict__ vals,
                                                          unsigned &mask, int lane){
  float bm=INFINITY; int ba=0;
  #pragma unroll
  for(int t=0;t<32;t++){
    if(!((mask>>t)&1u) && vals[t]<bm){ bm=vals[t]; ba=t; }
  }
  mask |= 1u<<ba;
  unsigned ub = __float_as_uint(bm);
  ub ^= (ub & 0x80000000u) ? 0xFFFFFFFFu : 0x80000000u;
  return ((unsigned long long)ub<<32) | (unsigned)(ba*64+lane);
}

// ---------------- K1: kNN — wave/query, u64-key tournament with per-lane cached top-4 ----------------
__global__ __launch_bounds__(256) void k_knn(const float4* __restrict__ ca, int* __restrict__ nbr){
  __shared__ float sx[NPER], sy[NPER], sz[NPER], sq[NPER];
  int wave = threadIdx.x>>6;
  int lane = threadIdx.x&63;
  int i = blockIdx.x*4 + wave;
  int batch = i / NPER;
  int base = batch*NPER;
  for(int t=threadIdx.x; t<NPER; t+=256){
    float4 c = ca[base+t];
    sx[t]=c.x; sy[t]=c.y; sz[t]=c.z; sq[t]=c.w;
  }
  __syncthreads();
  int il = i - base;
  float xi=sx[il], yi=sy[il], zi=sz[il], si=sq[il];
  float vals[32];
  #pragma unroll
  for(int t=0;t<32;t++){
    int j = t*64 + lane;
    float d2 = si + sq[j] - 2.0f*(xi*sx[j]+yi*sy[j]+zi*sz[j]);
    if(j==il) d2 = 1e30f;
    vals[t]=d2;
  }
  unsigned mask = 0;
  unsigned long long s0 = knn_extract(vals, mask, lane);
  unsigned long long s1 = knn_extract(vals, mask, lane);
  unsigned long long s2 = knn_extract(vals, mask, lane);
  unsigned long long s3 = knn_extract(vals, mask, lane);
  const unsigned long long EMPTY = ~0ull;
  for(int it=0; it<KNB; it++){
    unsigned long long m = s0;
    #pragma unroll
    for(int off=32; off>0; off>>=1){
      unsigned long long o = __shfl_xor(m, off, 64);
      m = (o<m) ? o : m;
    }
    if(lane==0) nbr[i*KNB+it] = base + (int)(m & 0x7FFull);
    if((int)(m & 63ull) == lane){
      s0=s1; s1=s2; s2=s3; s3=EMPTY;
      if(s0==EMPTY) s0 = knn_extract(vals, mask, lane);  // rare refill
    }
  }
}

// ---------------- K2a: trig table for positional embedding ----------------
__global__ void k_tbl(float* __restrict__ tbl){
  int i = blockIdx.x*256 + threadIdx.x;   // 4096*8 items
  int d = i>>3, m = i&7;
  float freq = __expf(-1.1512925465f*(float)m);  // 10000^(-m/8)
  float ang = (float)(d-2048)*freq;
  tbl[d*16+m]   = cosf(ang);
  tbl[d*16+8+m] = sinf(ang);
}

// ---------------- K2+K4a fused: edge features + both radial MLPs (ef computed in registers) ----------------
__global__ __launch_bounds__(128, 4)
void k_edgerad(const float4* __restrict__ ca, const int* __restrict__ nbr,
               const float* __restrict__ tbl,
               const float* __restrict__ bbw1, const float* __restrict__ bbw2,
               const float* __restrict__ latw1, const float* __restrict__ latw2,
               float* __restrict__ ef, float* __restrict__ radbb, float* __restrict__ radlat){
  int e = blockIdx.x*128 + threadIdx.x;
  int n = e/KNB;
  int j = nbr[e];
  float4 cn = ca[n], cj = ca[j];
  float dx=cn.x-cj.x, dy=cn.y-cj.y, dz=cn.z-cj.z;
  float dist = sqrtf(dx*dx+dy*dy+dz*dz + 1e-12f);
  float f[32];
  #pragma unroll
  for(int m=0;m<16;m++){
    float mu = (20.0f/15.0f)*(float)m;
    float t = (dist-mu)*(1.0f/1.25f);
    f[m] = __expf(-t*t);
  }
  {
    const float4* t4 = (const float4*)(tbl + (size_t)(j - n + 2048)*16);
    float4 c0=t4[0], c1=t4[1], s0=t4[2], s1=t4[3];
    f[16]=c0.x; f[17]=c0.y; f[18]=c0.z; f[19]=c0.w;
    f[20]=c1.x; f[21]=c1.y; f[22]=c1.z; f[23]=c1.w;
    f[24]=s0.x; f[25]=s0.y; f[26]=s0.z; f[27]=s0.w;
    f[28]=s1.x; f[29]=s1.y; f[30]=s1.z; f[31]=s1.w;
  }
  {
    float4* o4 = (float4*)(ef + (size_t)e*32);
    #pragma unroll
    for(int q=0;q<8;q++) o4[q] = make_float4(f[q*4],f[q*4+1],f[q*4+2],f[q*4+3]);
  }
  // ---- bb branch: 32->64(silu)->7 ----
  float ab[7];
  #pragma unroll
  for(int t=0;t<7;t++) ab[t]=0.f;
  #pragma unroll
  for(int half=0; half<2; half++){
    v2f h[16];
    #pragma unroll
    for(int o=0;o<16;o++) h[o]=splat2(0.f);
    #pragma unroll
    for(int c=0;c<32;c++){
      v2f fc = splat2(f[c]);
      const v2f* w = (const v2f*)(bbw1 + c*64 + half*32);
      #pragma unroll
      for(int o=0;o<16;o++) h[o] += fc*w[o];
    }
    #pragma unroll
    for(int o=0;o<16;o++){
      float v0 = siluf(h[o].x), v1 = siluf(h[o].y);
      const float* wa = bbw2 + (half*32+o*2)*7;
      const float* wb = bbw2 + (half*32+o*2+1)*7;
      #pragma unroll
      for(int t=0;t<7;t++) ab[t] += v0*wa[t];
      #pragma unroll
      for(int t=0;t<7;t++) ab[t] += v1*wb[t];
    }
  }
  {
    float4* rb4 = (float4*)(radbb + (size_t)e*8);
    rb4[0] = make_float4(ab[0],ab[1],ab[2],ab[3]);
    rb4[1] = make_float4(ab[4],ab[5],ab[6],0.f);
  }
  // ---- lat branch: 32->64(silu)->32 ----
  v2f al[16];
  #pragma unroll
  for(int t=0;t<16;t++) al[t]=splat2(0.f);
  #pragma unroll
  for(int half=0; half<2; half++){
    v2f h[16];
    #pragma unroll
    for(int o=0;o<16;o++) h[o]=splat2(0.f);
    #pragma unroll
    for(int c=0;c<32;c++){
      v2f fc = splat2(f[c]);
      const v2f* w = (const v2f*)(latw1 + c*64 + half*32);
      #pragma unroll
      for(int o=0;o<16;o++) h[o] += fc*w[o];
    }
    #pragma unroll
    for(int o=0;o<16;o++){
      float v0 = siluf(h[o].x), v1 = siluf(h[o].y);
      const v2f* wa = (const v2f*)(latw2 + (half*32+o*2)*32);
      const v2f* wb = (const v2f*)(latw2 + (half*32+o*2+1)*32);
      v2f va = splat2(v0), vb = splat2(v1);
      #pragma unroll
      for(int t=0;t<16;t++) al[t] += va*wa[t];
      #pragma unroll
      for(int t=0;t<16;t++) al[t] += vb*wb[t];
    }
  }
  v2f* rl2 = (v2f*)(radlat + (size_t)e*32);
  #pragma unroll
  for(int q=0;q<16;q++) rl2[q] = al[q];
}

// ---------------- K3: norm_so3 (latent only) ----------------
__global__ void k_norm(const float* __restrict__ in, float* __restrict__ out,
                       const float* __restrict__ g0, const float* __restrict__ b0,
                       const float* __restrict__ g1){
  int tid = blockIdx.x*256 + threadIdx.x;
  int n = tid >> 5, lane = tid & 31;
  if(n >= NRES) return;
  const float* xn = in + n*128;
  float x0 = xn[lane];
  float s = x0, s2 = x0*x0;
  for(int off=16; off>0; off>>=1){ s += __shfl_xor(s, off, 32); s2 += __shfl_xor(s2, off, 32); }
  float mu = s*(1.0f/32.0f);
  float var = s2*(1.0f/32.0f) - mu*mu;
  float y0 = (x0-mu)*rsqrtf(var+1e-6f)*g0[lane] + b0[lane];
  float v1 = xn[32+lane], v2 = xn[64+lane], v3 = xn[96+lane];
  float ss = v1*v1+v2*v2+v3*v3;
  for(int off=16; off>0; off>>=1){ ss += __shfl_xor(ss, off, 32); }
  float sc = rsqrtf(ss*(1.0f/96.0f) + 1e-6f);
  float g = g1[lane];
  out[n*128+lane]     = y0;
  out[n*128+32+lane]  = v1*sc*g;
  out[n*128+64+lane]  = v2*sc*g;
  out[n*128+96+lane]  = v3*sc*g;
}

// helper: load 32 floats into a register array (callers index with constants only)
__device__ __forceinline__ void load32(float* __restrict__ f, const float* __restrict__ src){
  const float4* s4 = (const float4*)src;
  #pragma unroll
  for(int q=0;q<8;q++){
    float4 v = s4[q];
    f[q*4+0]=v.x; f[q*4+1]=v.y; f[q*4+2]=v.z; f[q*4+3]=v.w;
  }
}

// ---------------- K4: init gather + out-proj + fused norm (wave/node) ----------------
__global__ __launch_bounds__(256) void k_init(const int* __restrict__ nbr,
                       const float* __restrict__ radbb, const float* __restrict__ radlat,
                       const float* __restrict__ bbf, const float* __restrict__ latn,
                       const float* __restrict__ bboutw, const float* __restrict__ latoutw,
                       const float* __restrict__ g0, const float* __restrict__ b0,
                       const float* __restrict__ g1,
                       float* __restrict__ x, float* __restrict__ xl){
  __shared__ float msgbb[4][32], msglat[4][128], xout[4][128];
  int g = threadIdx.x>>6, t = threadIdx.x&63;
  int n = blockIdx.x*4 + g;
  int t31 = t&31, t7 = t%7;
  float accL0=0.f, accL1=0.f, accB=0.f;
  for(int kk=0; kk<KNB; kk++){
    int e = n*KNB+kk;
    int j = nbr[e];
    float rl = radlat[(size_t)e*32 + t31];
    accL0 += latn[j*128+t]    * rl;
    accL1 += latn[j*128+64+t] * rl;
    if(t<28) accB += bbf[j*28+t]*radbb[(size_t)e*8 + t7];
  }
  msglat[g][t]=accL0*(1.0f/KNB); msglat[g][64+t]=accL1*(1.0f/KNB);
  if(t<28) msgbb[g][t]=accB*(1.0f/KNB);
  for(int half=0; half<2; half++){
    int e = half*64+t;
    int rrow = e>>5, c = e&31;
    float v=0.f;
    if(c<16){ for(int q=0;q<7;q++)  v += msgbb[g][rrow*7+q]*bboutw[q*16+c]; }
    else    { for(int q=0;q<32;q++) v += msglat[g][rrow*32+q]*latoutw[q*16+(c-16)]; }
    xout[g][e]=v;
    x[n*128+e]=v;
  }
  if(t<32){
    float x0=xout[g][t];
    float s=x0, s2=x0*x0;
    for(int off=16; off>0; off>>=1){ s+=__shfl_xor(s,off,32); s2+=__shfl_xor(s2,off,32); }
    float mu=s*(1.0f/32.0f), var=s2*(1.0f/32.0f)-mu*mu;
    float y0=(x0-mu)*rsqrtf(var+1e-6f)*g0[t]+b0[t];
    float v1=xout[g][32+t], v2=xout[g][64+t], v3=xout[g][96+t];
    float ss=v1*v1+v2*v2+v3*v3;
    for(int off=16; off>0; off>>=1) ss+=__shfl_xor(ss,off,32);
    float sc=rsqrtf(ss*(1.0f/96.0f)+1e-6f);
    float gg=g1[t];
    xl[n*128+t]=y0; xl[n*128+32+t]=v1*sc*gg; xl[n*128+64+t]=v2*sc*gg; xl[n*128+96+t]=v3*sc*gg;
  }
}

// ---------------- K4b0: layer-0 attn-logit per-node halves (asrc/adst only) ----------------
__global__ __launch_bounds__(256) void k_nodeprep0(const float* __restrict__ xl,
                       const float* __restrict__ aw1,
                       float* __restrict__ asrc, float* __restrict__ adst){
  __shared__ float sl[4][32];
  int g = threadIdx.x>>6, lane = threadIdx.x&63;
  int n = blockIdx.x*4 + g;
  if(lane<32) sl[g][lane] = xl[n*128+lane];
  __syncthreads();
  int o = lane&31;
  int roff = (lane>=32)? 32 : 0;
  float a=0.f;
  #pragma unroll
  for(int c=0;c<32;c++) a += sl[g][c]*aw1[(roff+c)*32+o];
  if(lane<32) asrc[n*32+o]=a; else adst[n*32+o]=a;
}

// ---------------- K5: attention logits (standalone, layer 0 only; v2f packed) ----------------
__global__ __launch_bounds__(128, 4)
void k_logits(const int* __restrict__ nbr,
              const float* __restrict__ asrc, const float* __restrict__ adst,
              const float* __restrict__ ef, const float* __restrict__ w1,
              const float* __restrict__ w2, float* __restrict__ logits){
  int e = blockIdx.x*128 + threadIdx.x;
  int n = e/KNB;
  int j = nbr[e];
  v2f h[16];
  {
    const v2f* pj = (const v2f*)(asrc + (size_t)j*32);
    const v2f* pn = (const v2f*)(adst + (size_t)n*32);
    #pragma unroll
    for(int q=0;q<16;q++) h[q] = pj[q]+pn[q];
  }
  float f[32];
  load32(f, ef + (size_t)e*32);
  #pragma unroll
  for(int c=0;c<32;c++){
    v2f fc = splat2(f[c]);
    const v2f* w = (const v2f*)(w1 + (64+c)*32);
    #pragma unroll
    for(int o=0;o<16;o++) h[o] += fc*w[o];
  }
  v2f acc[4];
  #pragma unroll
  for(int t=0;t<4;t++) acc[t]=splat2(0.f);
  #pragma unroll
  for(int o=0;o<16;o++){
    float v0 = siluf(h[o].x), v1 = siluf(h[o].y);
    const v2f* wa = (const v2f*)(w2 + (o*2)*8);
    const v2f* wb = (const v2f*)(w2 + (o*2+1)*8);
    v2f va = splat2(v0), vb = splat2(v1);
    #pragma unroll
    for(int t=0;t<4;t++) acc[t] += va*wa[t];
    #pragma unroll
    for(int t=0;t<4;t++) acc[t] += vb*wb[t];
  }
  v2f* lg2 = (v2f*)(logits + (size_t)e*8);
  #pragma unroll
  for(int q=0;q<4;q++) lg2[q] = acc[q];
}

// ---------------- K7: softmax + aggregate + o_w + FFN + norm + fused nodeprep tail ----------------
// All LDS regions are wave-private ([g]-indexed); wave-lockstep ordering => no barriers needed.
__global__ __launch_bounds__(256) void k_update(const int* __restrict__ nbr, const float* __restrict__ xl,
                         const float* __restrict__ logits, float* __restrict__ x,
                         float* __restrict__ xlout,
                         const float* __restrict__ vw, const float* __restrict__ ow,
                         const float* __restrict__ fw1, const float* __restrict__ fw2,
                         const float* __restrict__ fwg, const float* __restrict__ fv1,
                         const float* __restrict__ g0, const float* __restrict__ b0,
                         const float* __restrict__ g1,
                         const float* __restrict__ ew1l, const float* __restrict__ aw1n,
                         float* __restrict__ hsrc, float* __restrict__ hdst,
                         float* __restrict__ asrc, float* __restrict__ adst){
  __shared__ float S_lg[4][240], S_m[4][8], S_inv[4][8];
  __shared__ float S_S[4][1024], S_agg[4][512], S_x[4][128];
  __shared__ float S_h[4][64], S_g[4][32], S_d0[4][32], S_y0[4][32];
  int g = threadIdx.x>>6, t = threadIdx.x&63;
  int n = blockIdx.x*4 + g;
  for(int r=t; r<240; r+=64) S_lg[g][r] = logits[(size_t)n*240+r];
  if(t<8){
    float m=-1e30f;
    for(int kk=0;kk<KNB;kk++) m=fmaxf(m, S_lg[g][kk*8+t]);
    float s=0.f;
    for(int kk=0;kk<KNB;kk++) s += __expf(S_lg[g][kk*8+t]-m);
    S_m[g][t]=m; S_inv[g][t]=1.0f/s;
  }
  for(int r=t; r<240; r+=64){ int h=r&7; S_lg[g][r]=__expf(S_lg[g][r]-S_m[g][h])*S_inv[g][h]; }
  int hd = t>>3, i8 = t&7;
  const float4* xl4 = (const float4*)xl;
  float acc[16];
  for(int m=0;m<16;m++) acc[m]=0.f;
  for(int kk=0;kk<KNB;kk++){
    int j=nbr[n*KNB+kk];
    float a = S_lg[g][kk*8+hd];
    float4 b0v = xl4[j*32 + i8*4 + 0];
    float4 b1v = xl4[j*32 + i8*4 + 1];
    float4 b2v = xl4[j*32 + i8*4 + 2];
    float4 b3v = xl4[j*32 + i8*4 + 3];
    acc[0]+=a*b0v.x; acc[1]+=a*b0v.y; acc[2]+=a*b0v.z; acc[3]+=a*b0v.w;
    acc[4]+=a*b1v.x; acc[5]+=a*b1v.y; acc[6]+=a*b1v.z; acc[7]+=a*b1v.w;
    acc[8]+=a*b2v.x; acc[9]+=a*b2v.y; acc[10]+=a*b2v.z; acc[11]+=a*b2v.w;
    acc[12]+=a*b3v.x; acc[13]+=a*b3v.y; acc[14]+=a*b3v.z; acc[15]+=a*b3v.w;
  }
  for(int m=0;m<16;m++) S_S[g][hd*128 + i8*16 + m] = acc[m];
  for(int half=0; half<2; half++){
    int hv = half*64+t;
    int hh = hv>>4;
    float a0=0.f,a1=0.f,a2=0.f,a3=0.f;
    for(int c=0;c<32;c++){
      float w = vw[c*128+hv];
      a0 += S_S[g][hh*128 + c]*w;
      a1 += S_S[g][hh*128 + 32+c]*w;
      a2 += S_S[g][hh*128 + 64+c]*w;
      a3 += S_S[g][hh*128 + 96+c]*w;
    }
    S_agg[g][hv]=a0; S_agg[g][128+hv]=a1; S_agg[g][256+hv]=a2; S_agg[g][384+hv]=a3;
  }
  for(int half=0; half<2; half++){
    int e = half*64+t;
    int rrow = e>>5, c = e&31;
    float v = x[n*128+e];
    for(int hv=0;hv<128;hv++) v += S_agg[g][rrow*128+hv]*ow[hv*32+c];
    S_x[g][e]=v;
  }
  {
    float hs=0.f;
    for(int c=0;c<32;c++) hs += S_x[g][c]*fw1[c*64+t];
    S_h[g][t]=siluf(hs);
  }
  if(t<32){
    float gs=0.f, d0=0.f;
    for(int c=0;c<64;c++){ float hv=S_h[g][c]; gs += hv*fwg[c*32+t]; d0 += hv*fw2[c*32+t]; }
    S_g[g][t]=1.0f/(1.0f+__expf(-gs));
    S_d0[g][t]=d0;
  }
  for(int half=0; half<2; half++){
    int e = half*64+t;
    int rrow = e>>5, c = e&31;
    float xv = S_x[g][e], outv;
    if(rrow==0){ outv = xv + S_d0[g][c]; }
    else {
      float dv=0.f;
      for(int cc=0;cc<32;cc++) dv += S_x[g][rrow*32+cc]*fv1[cc*32+c];
      outv = xv + dv*S_g[g][c];
    }
    S_x[g][e]=outv;
    x[n*128+e]=outv;
  }
  if(t<32){
    float x0=S_x[g][t];
    float s=x0, s2=x0*x0;
    for(int off=16; off>0; off>>=1){ s+=__shfl_xor(s,off,32); s2+=__shfl_xor(s2,off,32); }
    float mu=s*(1.0f/32.0f), var=s2*(1.0f/32.0f)-mu*mu;
    float y0=(x0-mu)*rsqrtf(var+1e-6f)*g0[t]+b0[t];
    float v1=S_x[g][32+t], v2=S_x[g][64+t], v3=S_x[g][96+t];
    float ss=v1*v1+v2*v2+v3*v3;
    for(int off=16; off>0; off>>=1) ss+=__shfl_xor(ss,off,32);
    float sc=rsqrtf(ss*(1.0f/96.0f)+1e-6f);
    float gg=g1[t];
    xlout[n*128+t]=y0; xlout[n*128+32+t]=v1*sc*gg;
    xlout[n*128+64+t]=v2*sc*gg; xlout[n*128+96+t]=v3*sc*gg;
    S_y0[g][t]=y0;
  }
  // ---- fused nodeprep tail (same arithmetic/order as the old standalone k_nodeprep) ----
  {
    float a0=0.f, a1=0.f;
    #pragma unroll
    for(int c=0;c<32;c++){
      float xv = S_x[g][c];
      a0 += xv*ew1l[(32+c)*64+t];
      a1 += xv*ew1l[(64+c)*64+t];
    }
    hsrc[n*64+t]=a0; hdst[n*64+t]=a1;
  }
  if(aw1n){
    int o = t&31;
    int roff = (t>=32)? 32 : 0;
    float a=0.f;
    #pragma unroll
    for(int c=0;c<32;c++) a += S_y0[g][c]*aw1n[(roff+c)*32+o];
    if(t<32) asrc[n*32+o]=a; else adst[n*32+o]=a;
  }
}

// ---------------- K8: edge update + next-layer logits (layers 0..2); v2f, o-halved ----------------
__global__ __launch_bounds__(128, 4)
void k_efup(const int* __restrict__ nbr,
            const float* __restrict__ hsrc, const float* __restrict__ hdst,
            const float* __restrict__ ew1, const float* __restrict__ ew2,
            float* __restrict__ ef,
            const float* __restrict__ asrc, const float* __restrict__ adst,
            const float* __restrict__ aw1n, const float* __restrict__ aw2n,
            float* __restrict__ logits){
  int e = blockIdx.x*128 + threadIdx.x;
  int n = e/KNB;
  int j = nbr[e];
  float f[32];
  load32(f, ef + (size_t)e*32);
  v2f acc[16];
  #pragma unroll
  for(int t=0;t<16;t++) acc[t]=splat2(0.f);
  #pragma unroll
  for(int half=0; half<2; half++){
    v2f h[16];
    {
      const v2f* pj = (const v2f*)(hsrc + (size_t)j*64 + half*32);
      const v2f* pn = (const v2f*)(hdst + (size_t)n*64 + half*32);
      #pragma unroll
      for(int q=0;q<16;q++) h[q] = pj[q]+pn[q];
    }
    #pragma unroll
    for(int c=0;c<32;c++){
      v2f fc = splat2(f[c]);
      const v2f* w = (const v2f*)(ew1 + c*64 + half*32);
      #pragma unroll
      for(int o=0;o<16;o++) h[o] += fc*w[o];
    }
    #pragma unroll
    for(int o=0;o<16;o++){
      float v0 = siluf(h[o].x), v1 = siluf(h[o].y);
      const v2f* wa = (const v2f*)(ew2 + (half*32+o*2)*32);
      const v2f* wb = (const v2f*)(ew2 + (half*32+o*2+1)*32);
      v2f va = splat2(v0), vb = splat2(v1);
      #pragma unroll
      for(int t=0;t<16;t++) acc[t] += va*wa[t];
      #pragma unroll
      for(int t=0;t<16;t++) acc[t] += vb*wb[t];
    }
  }
  #pragma unroll
  for(int t=0;t<16;t++){ f[2*t] += acc[t].x; f[2*t+1] += acc[t].y; }
  float4* e4 = (float4*)(ef + (size_t)e*32);
  #pragma unroll
  for(int q=0;q<8;q++)
    e4[q] = make_float4(f[q*4+0], f[q*4+1], f[q*4+2], f[q*4+3]);
  // next-layer logits on (asrc[j]+adst[n], new ef)
  v2f h2[16];
  {
    const v2f* pj = (const v2f*)(asrc + (size_t)j*32);
    const v2f* pn = (const v2f*)(adst + (size_t)n*32);
    #pragma unroll
    for(int q=0;q<16;q++) h2[q] = pj[q]+pn[q];
  }
  #pragma unroll
  for(int c=0;c<32;c++){
    v2f fc = splat2(f[c]);
    const v2f* w = (const v2f*)(aw1n + (64+c)*32);
    #pragma unroll
    for(int o=0;o<16;o++) h2[o] += fc*w[o];
  }
  v2f a8[4];
  #pragma unroll
  for(int t=0;t<4;t++) a8[t]=splat2(0.f);
  #pragma unroll
  for(int o=0;o<16;o++){
    float v0 = siluf(h2[o].x), v1 = siluf(h2[o].y);
    const v2f* wa = (const v2f*)(aw2n + (o*2)*8);
    const v2f* wb = (const v2f*)(aw2n + (o*2+1)*8);
    v2f va = splat2(v0), vb = splat2(v1);
    #pragma unroll
    for(int t=0;t<4;t++) a8[t] += va*wa[t];
    #pragma unroll
    for(int t=0;t<4;t++) a8[t] += vb*wb[t];
  }
  v2f* lg2 = (v2f*)(logits + (size_t)e*8);
  #pragma unroll
  for(int q=0;q<4;q++) lg2[q] = a8[q];
}

// ---------------- K8b: layer-3 edge update + out radial MLP fused; writes orad IN-PLACE over ef ----------------
__global__ __launch_bounds__(128, 4)
void k_efup_orad(const int* __restrict__ nbr,
                 const float* __restrict__ hsrc, const float* __restrict__ hdst,
                 const float* __restrict__ ew1, const float* __restrict__ ew2,
                 float* __restrict__ ef,
                 const float* __restrict__ orw1, const float* __restrict__ orw2){
  int e = blockIdx.x*128 + threadIdx.x;
  int n = e/KNB;
  int j = nbr[e];
  float f[32];
  load32(f, ef + (size_t)e*32);
  v2f acc[16];
  #pragma unroll
  for(int t=0;t<16;t++) acc[t]=splat2(0.f);
  #pragma unroll
  for(int half=0; half<2; half++){
    v2f h[16];
    {
      const v2f* pj = (const v2f*)(hsrc + (size_t)j*64 + half*32);
      const v2f* pn = (const v2f*)(hdst + (size_t)n*64 + half*32);
      #pragma unroll
      for(int q=0;q<16;q++) h[q] = pj[q]+pn[q];
    }
    #pragma unroll
    for(int c=0;c<32;c++){
      v2f fc = splat2(f[c]);
      const v2f* w = (const v2f*)(ew1 + c*64 + half*32);
      #pragma unroll
      for(int o=0;o<16;o++) h[o] += fc*w[o];
    }
    #pragma unroll
    for(int o=0;o<16;o++){
      float v0 = siluf(h[o].x), v1 = siluf(h[o].y);
      const v2f* wa = (const v2f*)(ew2 + (half*32+o*2)*32);
      const v2f* wb = (const v2f*)(ew2 + (half*32+o*2+1)*32);
      v2f va = splat2(v0), vb = splat2(v1);
      #pragma unroll
      for(int t=0;t<16;t++) acc[t] += va*wa[t];
      #pragma unroll
      for(int t=0;t<16;t++) acc[t] += vb*wb[t];
    }
  }
  // new ef (layer 3) kept in registers only — its sole consumer is the orad MLP below
  #pragma unroll
  for(int t=0;t<16;t++){ f[2*t] += acc[t].x; f[2*t+1] += acc[t].y; }
  // out radial MLP: 32->64(silu)->32 on new ef
  v2f oa[16];
  #pragma unroll
  for(int t=0;t<16;t++) oa[t]=splat2(0.f);
  #pragma unroll
  for(int half=0; half<2; half++){
    v2f h[16];
    #pragma unroll
    for(int o=0;o<16;o++) h[o]=splat2(0.f);
    #pragma unroll
    for(int c=0;c<32;c++){
      v2f fc = splat2(f[c]);
      const v2f* w = (const v2f*)(orw1 + c*64 + half*32);
      #pragma unroll
      for(int o=0;o<16;o++) h[o] += fc*w[o];
    }
    #pragma unroll
    for(int o=0;o<16;o++){
      float v0 = siluf(h[o].x), v1 = siluf(h[o].y);
      const v2f* wa = (const v2f*)(orw2 + (half*32+o*2)*32);
      const v2f* wb = (const v2f*)(orw2 + (half*32+o*2+1)*32);
      v2f va = splat2(v0), vb = splat2(v1);
      #pragma unroll
      for(int t=0;t<16;t++) oa[t] += va*wa[t];
      #pragma unroll
      for(int t=0;t<16;t++) oa[t] += vb*wb[t];
    }
  }
  // in-place: thread e owns slot e of ef; write orad there (ef dead afterwards)
  v2f* r2 = (v2f*)(ef + (size_t)e*32);
  #pragma unroll
  for(int q=0;q<16;q++) r2[q] = oa[q];
}

// ---------------- K9: out gather + projection + fused seq head ----------------
__global__ __launch_bounds__(256) void k_out(const int* __restrict__ nbr, const float* __restrict__ orad,
                      const float* __restrict__ x,
                      const float* __restrict__ outw,
                      const float* __restrict__ sw1, const float* __restrict__ sb1,
                      const float* __restrict__ sw2, const float* __restrict__ sb2,
                      const float* __restrict__ sw3, const float* __restrict__ sb3,
                      float* __restrict__ out, float* __restrict__ outseq){
  __shared__ float msg[4][128];
  __shared__ float h1[4][64], h2[4][32], lgs[4][20];
  int g = threadIdx.x>>6, t = threadIdx.x&63;
  int n = blockIdx.x*4 + g;
  int t31 = t&31;
  float acc0=0.f, acc1=0.f;
  for(int kk=0;kk<KNB;kk++){
    int e=n*KNB+kk;
    int j=nbr[e];
    float rl = orad[(size_t)e*32 + t31];
    acc0 += x[j*128+t]*rl;
    acc1 += x[j*128+64+t]*rl;
  }
  msg[g][t]=acc0*(1.0f/KNB); msg[g][64+t]=acc1*(1.0f/KNB);
  for(int o=t;o<91;o+=64){
    for(int rrow=1;rrow<4;rrow++){
      float s=0.f;
      for(int c=0;c<32;c++) s += msg[g][rrow*32+c]*outw[c*91+o];
      out[(size_t)n*273 + o*3 + (rrow-1)] = s;
    }
  }
  {
    float s=0.f;
    for(int c=0;c<32;c++) s += x[n*128+c]*sw1[c*64+t];
    h1[g][t]=fmaxf(s+sb1[t],0.f);
  }
  if(t<32){
    float s=0.f;
    for(int c=0;c<64;c++) s += h1[g][c]*sw2[c*32+t];
    h2[g][t]=fmaxf(s+sb2[t],0.f);
  }
  if(t<20){
    float s=0.f;
    for(int c=0;c<32;c++) s += h2[g][c]*sw3[c*20+t];
    lgs[g][t]=s+sb3[t];
  }
  if(t<20){
    float m=-1e30f;
    for(int c=0;c<20;c++) m=fmaxf(m,lgs[g][c]);
    float se=0.f;
    for(int c=0;c<20;c++) se += __expf(lgs[g][c]-m);
    outseq[(size_t)n*20+t]=lgs[g][t]-m-logf(se);
  }
}

extern "C" void kernel_launch(void* const* d_in, const int* in_sizes, int n_in,
                              void* d_out, int out_size, void* d_ws, size_t ws_size,
                              hipStream_t stream) {
  const float* bb      = (const float*)d_in[0];
  const float* latent  = (const float*)d_in[1];
  const float* ln_g0   = (const float*)d_in[2];
  const float* ln_b0   = (const float*)d_in[3];
  const float* ln_g1   = (const float*)d_in[4];
  const float* bbw1    = (const float*)d_in[5];
  const float* bbw2    = (const float*)d_in[6];
  const float* bboutw  = (const float*)d_in[7];
  const float* latw1   = (const float*)d_in[8];
  const float* latw2   = (const float*)d_in[9];
  const float* latoutw = (const float*)d_in[10];
  const float* tg0     = (const float*)d_in[11];
  const float* tb0     = (const float*)d_in[12];
  const float* tg1     = (const float*)d_in[13];
  const float* aw1     = (const float*)d_in[14];
  const float* aw2     = (const float*)d_in[15];
  const float* vw      = (const float*)d_in[16];
  const float* ow      = (const float*)d_in[17];
  const float* fw1     = (const float*)d_in[18];
  const float* fw2     = (const float*)d_in[19];
  const float* fwg     = (const float*)d_in[20];
  const float* fv1     = (const float*)d_in[21];
  const float* ew1     = (const float*)d_in[22];
  const float* ew2     = (const float*)d_in[23];
  const float* orw1    = (const float*)d_in[24];
  const float* orw2    = (const float*)d_in[25];
  const float* outw    = (const float*)d_in[26];
  const float* sw1     = (const float*)d_in[27];
  const float* sb1     = (const float*)d_in[28];
  const float* sw2     = (const float*)d_in[29];
  const float* sb2     = (const float*)d_in[30];
  const float* sw3     = (const float*)d_in[31];
  const float* sb3     = (const float*)d_in[32];
  float* outp = (float*)d_out;

  // workspace layout (radbb overlays logits; radlat + nodeprep arrays overlay edgescratch;
  // tbl overlays xbuf (dead until k_init); orad written in-place over ef by k_efup_orad)
  int*    nbr    = (int*)d_ws;
  float*  ef     = (float*)((char*)d_ws + 1024*1024);
  float*  xbuf   = ef   + (size_t)NEDGE*32;
  float*  xlA    = xbuf + (size_t)NRES*128;
  float*  xlB    = xlA  + (size_t)NRES*128;
  float*  bbf    = xlB  + (size_t)NRES*128;
  float*  logits = bbf  + (size_t)NRES*28;
  float4* ca     = (float4*)(logits + (size_t)NEDGE*8);
  float*  edgescratch = (float*)(ca + NRES);     // NEDGE*32 floats
  float*  radbb  = logits;                       // NEDGE*8, dead before first k_logits
  float*  radlat = edgescratch;                  // NEDGE*32, dead after k_init
  float*  tbl    = xbuf;                         // 4096*16 floats, xbuf dead until k_init
  // per-node hoisted arrays: live only between k_init and k_efup_orad (radlat dead window)
  float*  hsrc   = edgescratch;                              // NRES*64
  float*  hdst   = edgescratch + (size_t)NRES*64;            // NRES*64
  float*  asrc   = edgescratch + (size_t)NRES*128;           // NRES*32
  float*  adst   = edgescratch + (size_t)NRES*128 + (size_t)NRES*32; // NRES*32

  k_bbfeat  <<<NRES/256, 256, 0, stream>>>(bb, bbf, ca);
  k_knn     <<<NRES/4,   256, 0, stream>>>(ca, nbr);
  k_tbl     <<<4096*8/256, 256, 0, stream>>>(tbl);
  k_edgerad <<<NEDGE/128, 128, 0, stream>>>(ca, nbr, tbl, bbw1, bbw2, latw1, latw2,
                                            ef, radbb, radlat);
  k_norm    <<<NRES*32/256, 256, 0, stream>>>(latent, xlA, ln_g0, ln_b0, ln_g1);
  k_init    <<<NRES/4, 256, 0, stream>>>(nbr, radbb, radlat, bbf, xlA,
                                         bboutw, latoutw,
                                         tg0, tb0, tg1,
                                         xbuf, xlB);
  // layer-0 logits: per-node halves (standalone — avoids racing radlat overlay inside k_init)
  k_nodeprep0<<<NRES/4, 256, 0, stream>>>(xlB, aw1, asrc, adst);
  k_logits   <<<NEDGE/128, 128, 0, stream>>>(nbr, asrc, adst, ef, aw1, aw2, logits);
  for(int l=0;l<4;l++){
    const float* xl_in  = (l&1) ? xlA : xlB;
    float*       xl_out = (l&1) ? xlB : xlA;
    int ln = (l+1<4) ? (l+1) : 3;
    const float* aw1n = (l<3) ? (aw1+(l+1)*96*32) : nullptr;
    k_update <<<NRES/4, 256, 0, stream>>>(nbr, xl_in, logits, xbuf, xl_out,
                                          vw+l*32*128, ow+l*128*32,
                                          fw1+l*32*64, fw2+l*64*32,
                                          fwg+l*64*32, fv1+l*32*32,
                                          tg0+ln*32, tb0+ln*32, tg1+ln*32,
                                          ew1+l*96*64, aw1n,
                                          hsrc, hdst, asrc, adst);
    if(l<3){
      k_efup<<<NEDGE/128, 128, 0, stream>>>(nbr, hsrc, hdst,
                                            ew1+l*96*64, ew2+l*64*32, ef,
                                            asrc, adst,
                                            aw1+(l+1)*96*32, aw2+(l+1)*32*8, logits);
    } else {
      k_efup_orad<<<NEDGE/128, 128, 0, stream>>>(nbr, hsrc, hdst,
                                                 ew1+l*96*64, ew2+l*64*32, ef,
                                                 orw1, orw2);
    }
  }
  k_out <<<NRES/4, 256, 0, stream>>>(nbr, ef /*orad in-place*/, xbuf, outw,
                                     sw1, sb1, sw2, sb2, sw3, sb3,
                                     outp, outp + (size_t)NRES*273);
}

// Round 7
// 1139.873 us; speedup vs baseline: 1.3896x; 1.0616x over previous
//
#include <hip/hip_runtime.h>
#include <math.h>

#define NRES 8192
#define NPER 2048
#define KNB  30
#define NEDGE (NRES*KNB)

typedef float v2f __attribute__((ext_vector_type(2)));

__device__ __forceinline__ float siluf(float x){ return x / (1.0f + __expf(-x)); }
__device__ __forceinline__ v2f splat2(float a){ v2f r; r.x=a; r.y=a; return r; }

// ---------------- K0: backbone features + ca pack ----------------
__global__ void k_bbfeat(const float* __restrict__ bb, float* __restrict__ bbf,
                         float4* __restrict__ ca){
  int n = blockIdx.x*256 + threadIdx.x;
  if(n >= NRES) return;
  const float* r = bb + n*12;
  float cax=r[3], cay=r[4], caz=r[5];
  ca[n] = make_float4(cax,cay,caz, cax*cax+cay*cay+caz*caz);
  float vx[7],vy[7],vz[7];
  for(int a=0;a<4;a++){ vx[a]=r[a*3]-cax; vy[a]=r[a*3+1]-cay; vz[a]=r[a*3+2]-caz; }
  if(n<NRES-1){
    float dx=bb[(n+1)*12+3]-cax, dy=bb[(n+1)*12+4]-cay, dz=bb[(n+1)*12+5]-caz;
    float s=rsqrtf(dx*dx+dy*dy+dz*dz+1e-8f);
    vx[4]=dx*s; vy[4]=dy*s; vz[4]=dz*s;
  } else { vx[4]=0.f; vy[4]=0.f; vz[4]=0.f; }
  if(n>0){
    float dx=bb[(n-1)*12+3]-cax, dy=bb[(n-1)*12+4]-cay, dz=bb[(n-1)*12+5]-caz;
    float s=rsqrtf(dx*dx+dy*dy+dz*dz+1e-8f);
    vx[5]=dx*s; vy[5]=dy*s; vz[5]=dz*s;
  } else { vx[5]=0.f; vy[5]=0.f; vz[5]=0.f; }
  {
    float bx=cax-r[0], by=cay-r[1], bz=caz-r[2];
    float cx=r[6]-cax, cy=r[7]-cay, cz=r[8]-caz;
    float axx=by*cz-bz*cy, ayy=bz*cx-bx*cz, azz=bx*cy-by*cx;
    vx[6]=-0.58273431f*axx+0.56802827f*bx-0.54067466f*cx;
    vy[6]=-0.58273431f*ayy+0.56802827f*by-0.54067466f*cy;
    vz[6]=-0.58273431f*azz+0.56802827f*bz-0.54067466f*cz;
  }
  float cD[3], sD[3];
  for(int t=0;t<3;t++){
    cD[t]=1.0f; sD[t]=0.0f;
    int f=3*n+t-1;
    if(f>=0 && f<3*NRES-3){
      float X[4][3];
      for(int q=0;q<4;q++){
        int m=f+q, rr=m/3, aa=m-rr*3;
        X[q][0]=bb[rr*12+aa*3]; X[q][1]=bb[rr*12+aa*3+1]; X[q][2]=bb[rr*12+aa*3+2];
      }
      float u2x=X[1][0]-X[0][0], u2y=X[1][1]-X[0][1], u2z=X[1][2]-X[0][2];
      float u1x=X[2][0]-X[1][0], u1y=X[2][1]-X[1][1], u1z=X[2][2]-X[1][2];
      float u0x=X[3][0]-X[2][0], u0y=X[3][1]-X[2][1], u0z=X[3][2]-X[2][2];
      float s2=rsqrtf(u2x*u2x+u2y*u2y+u2z*u2z+1e-8f); u2x*=s2; u2y*=s2; u2z*=s2;
      float s1=rsqrtf(u1x*u1x+u1y*u1y+u1z*u1z+1e-8f); u1x*=s1; u1y*=s1; u1z*=s1;
      float s0=rsqrtf(u0x*u0x+u0y*u0y+u0z*u0z+1e-8f); u0x*=s0; u0y*=s0; u0z*=s0;
      float n2x=u2y*u1z-u2z*u1y, n2y=u2z*u1x-u2x*u1z, n2z=u2x*u1y-u2y*u1x;
      float nn2=rsqrtf(n2x*n2x+n2y*n2y+n2z*n2z+1e-8f); n2x*=nn2; n2y*=nn2; n2z*=nn2;
      float n1x=u1y*u0z-u1z*u0y, n1y=u1z*u0x-u1x*u0z, n1z=u1x*u0y-u1y*u0x;
      float nn1=rsqrtf(n1x*n1x+n1y*n1y+n1z*n1z+1e-8f); n1x*=nn1; n1y*=nn1; n1z*=nn1;
      float dotn = n2x*n1x+n2y*n1y+n2z*n1z;
      float cosD = fminf(fmaxf(dotn, -1.0f+1e-6f), 1.0f-1e-6f);
      float sg = u2x*n1x+u2y*n1y+u2z*n1z;
      if(sg==0.0f){ cD[t]=1.0f; sD[t]=0.0f; }
      else {
        float sgn = (sg>0.0f)?1.0f:-1.0f;
        cD[t]=cosD;
        sD[t]=sgn*sqrtf(fmaxf(1.0f-cosD*cosD,0.0f));
      }
    }
  }
  float* o = bbf + n*28;
  o[0]=cD[0]; o[1]=cD[1]; o[2]=cD[2]; o[3]=sD[0]; o[4]=sD[1]; o[5]=sD[2]; o[6]=0.f;
  for(int c=0;c<7;c++){ o[7+c]=vx[c]; o[14+c]=vy[c]; o[21+c]=vz[c]; }
}

// helper: per-lane extraction of the next-smallest unconsumed value as packed u64 key.
__device__ __forceinline__ unsigned long long knn_extract(const float* __restrict__ vals,
                                                          unsigned &mask, int lane){
  float bm=INFINITY; int ba=0;
  #pragma unroll
  for(int t=0;t<32;t++){
    if(!((mask>>t)&1u) && vals[t]<bm){ bm=vals[t]; ba=t; }
  }
  mask |= 1u<<ba;
  unsigned ub = __float_as_uint(bm);
  ub ^= (ub & 0x80000000u) ? 0xFFFFFFFFu : 0x80000000u;
  return ((unsigned long long)ub<<32) | (unsigned)(ba*64+lane);
}

// ---------------- K1: kNN — wave/query, u64-key tournament with per-lane cached top-4 ----------------
__global__ __launch_bounds__(256) void k_knn(const float4* __restrict__ ca, int* __restrict__ nbr){
  __shared__ float sx[NPER], sy[NPER], sz[NPER], sq[NPER];
  int wave = threadIdx.x>>6;
  int lane = threadIdx.x&63;
  int i = blockIdx.x*4 + wave;
  int batch = i / NPER;
  int base = batch*NPER;
  for(int t=threadIdx.x; t<NPER; t+=256){
    float4 c = ca[base+t];
    sx[t]=c.x; sy[t]=c.y; sz[t]=c.z; sq[t]=c.w;
  }
  __syncthreads();
  int il = i - base;
  float xi=sx[il], yi=sy[il], zi=sz[il], si=sq[il];
  float vals[32];
  #pragma unroll
  for(int t=0;t<32;t++){
    int j = t*64 + lane;
    float d2 = si + sq[j] - 2.0f*(xi*sx[j]+yi*sy[j]+zi*sz[j]);
    if(j==il) d2 = 1e30f;
    vals[t]=d2;
  }
  unsigned mask = 0;
  unsigned long long s0 = knn_extract(vals, mask, lane);
  unsigned long long s1 = knn_extract(vals, mask, lane);
  unsigned long long s2 = knn_extract(vals, mask, lane);
  unsigned long long s3 = knn_extract(vals, mask, lane);
  const unsigned long long EMPTY = ~0ull;
  for(int it=0; it<KNB; it++){
    unsigned long long m = s0;
    #pragma unroll
    for(int off=32; off>0; off>>=1){
      unsigned long long o = __shfl_xor(m, off, 64);
      m = (o<m) ? o : m;
    }
    if(lane==0) nbr[i*KNB+it] = base + (int)(m & 0x7FFull);
    if((int)(m & 63ull) == lane){
      s0=s1; s1=s2; s2=s3; s3=EMPTY;
      if(s0==EMPTY) s0 = knn_extract(vals, mask, lane);  // rare refill
    }
  }
}

// ---------------- K2a: trig table for positional embedding ----------------
__global__ void k_tbl(float* __restrict__ tbl){
  int i = blockIdx.x*256 + threadIdx.x;   // 4096*8 items
  int d = i>>3, m = i&7;
  float freq = __expf(-1.1512925465f*(float)m);  // 10000^(-m/8)
  float ang = (float)(d-2048)*freq;
  tbl[d*16+m]   = cosf(ang);
  tbl[d*16+8+m] = sinf(ang);
}

// ---------------- K2: edge features ef (N,k,32) = [rbf16, cos8, sin8] ----------------
__global__ void k_edgefeat(const float4* __restrict__ ca, const int* __restrict__ nbr,
                           const float* __restrict__ tbl, float* __restrict__ ef){
  int e = blockIdx.x*256 + threadIdx.x;
  if(e >= NEDGE) return;
  int n = e/KNB;
  int j = nbr[e];
  float4 cn = ca[n], cj = ca[j];
  float dx=cn.x-cj.x, dy=cn.y-cj.y, dz=cn.z-cj.z;
  float dist = sqrtf(dx*dx+dy*dy+dz*dz + 1e-12f);
  float f[32];
  #pragma unroll
  for(int m=0;m<16;m++){
    float mu = (20.0f/15.0f)*(float)m;
    float t = (dist-mu)*(1.0f/1.25f);
    f[m] = __expf(-t*t);
  }
  {
    const float4* t4 = (const float4*)(tbl + (size_t)(j - n + 2048)*16);
    float4 c0=t4[0], c1=t4[1], s0=t4[2], s1=t4[3];
    f[16]=c0.x; f[17]=c0.y; f[18]=c0.z; f[19]=c0.w;
    f[20]=c1.x; f[21]=c1.y; f[22]=c1.z; f[23]=c1.w;
    f[24]=s0.x; f[25]=s0.y; f[26]=s0.z; f[27]=s0.w;
    f[28]=s1.x; f[29]=s1.y; f[30]=s1.z; f[31]=s1.w;
  }
  float4* o4 = (float4*)(ef + (size_t)e*32);
  #pragma unroll
  for(int q=0;q<8;q++) o4[q] = make_float4(f[q*4],f[q*4+1],f[q*4+2],f[q*4+3]);
}

// ---------------- K3: norm_so3 (latent only) ----------------
__global__ void k_norm(const float* __restrict__ in, float* __restrict__ out,
                       const float* __restrict__ g0, const float* __restrict__ b0,
                       const float* __restrict__ g1){
  int tid = blockIdx.x*256 + threadIdx.x;
  int n = tid >> 5, lane = tid & 31;
  if(n >= NRES) return;
  const float* xn = in + n*128;
  float x0 = xn[lane];
  float s = x0, s2 = x0*x0;
  for(int off=16; off>0; off>>=1){ s += __shfl_xor(s, off, 32); s2 += __shfl_xor(s2, off, 32); }
  float mu = s*(1.0f/32.0f);
  float var = s2*(1.0f/32.0f) - mu*mu;
  float y0 = (x0-mu)*rsqrtf(var+1e-6f)*g0[lane] + b0[lane];
  float v1 = xn[32+lane], v2 = xn[64+lane], v3 = xn[96+lane];
  float ss = v1*v1+v2*v2+v3*v3;
  for(int off=16; off>0; off>>=1){ ss += __shfl_xor(ss, off, 32); }
  float sc = rsqrtf(ss*(1.0f/96.0f) + 1e-6f);
  float g = g1[lane];
  out[n*128+lane]     = y0;
  out[n*128+32+lane]  = v1*sc*g;
  out[n*128+64+lane]  = v2*sc*g;
  out[n*128+96+lane]  = v3*sc*g;
}

// helper: load 32 floats into a register array (callers index with constants only)
__device__ __forceinline__ void load32(float* __restrict__ f, const float* __restrict__ src){
  const float4* s4 = (const float4*)src;
  #pragma unroll
  for(int q=0;q<8;q++){
    float4 v = s4[q];
    f[q*4+0]=v.x; f[q*4+1]=v.y; f[q*4+2]=v.z; f[q*4+3]=v.w;
  }
}

// ---------------- K4a: init radial MLPs, lane-per-edge, v2f packed FMA ----------------
__global__ __launch_bounds__(128, 4)
void k_rad(const float* __restrict__ ef,
           const float* __restrict__ bbw1, const float* __restrict__ bbw2,
           const float* __restrict__ latw1, const float* __restrict__ latw2,
           float* __restrict__ radbb, float* __restrict__ radlat){
  int e = blockIdx.x*128 + threadIdx.x;
  float f[32];
  load32(f, ef + (size_t)e*32);
  // ---- bb branch: 32->64(silu)->7, o in two halves of 32 (same FP order) ----
  float ab[7];
  #pragma unroll
  for(int t=0;t<7;t++) ab[t]=0.f;
  #pragma unroll
  for(int half=0; half<2; half++){
    v2f h[16];
    #pragma unroll
    for(int o=0;o<16;o++) h[o]=splat2(0.f);
    #pragma unroll
    for(int c=0;c<32;c++){
      v2f fc = splat2(f[c]);
      const v2f* w = (const v2f*)(bbw1 + c*64 + half*32);
      #pragma unroll
      for(int o=0;o<16;o++) h[o] += fc*w[o];
    }
    #pragma unroll
    for(int o=0;o<16;o++){
      float v0 = siluf(h[o].x), v1 = siluf(h[o].y);
      const float* wa = bbw2 + (half*32+o*2)*7;
      const float* wb = bbw2 + (half*32+o*2+1)*7;
      #pragma unroll
      for(int t=0;t<7;t++) ab[t] += v0*wa[t];
      #pragma unroll
      for(int t=0;t<7;t++) ab[t] += v1*wb[t];
    }
  }
  {
    float4* rb4 = (float4*)(radbb + (size_t)e*8);
    rb4[0] = make_float4(ab[0],ab[1],ab[2],ab[3]);
    rb4[1] = make_float4(ab[4],ab[5],ab[6],0.f);
  }
  // ---- lat branch: 32->64(silu)->32, o-halved, v2f ----
  v2f al[16];
  #pragma unroll
  for(int t=0;t<16;t++) al[t]=splat2(0.f);
  #pragma unroll
  for(int half=0; half<2; half++){
    v2f h[16];
    #pragma unroll
    for(int o=0;o<16;o++) h[o]=splat2(0.f);
    #pragma unroll
    for(int c=0;c<32;c++){
      v2f fc = splat2(f[c]);
      const v2f* w = (const v2f*)(latw1 + c*64 + half*32);
      #pragma unroll
      for(int o=0;o<16;o++) h[o] += fc*w[o];
    }
    #pragma unroll
    for(int o=0;o<16;o++){
      float v0 = siluf(h[o].x), v1 = siluf(h[o].y);
      const v2f* wa = (const v2f*)(latw2 + (half*32+o*2)*32);
      const v2f* wb = (const v2f*)(latw2 + (half*32+o*2+1)*32);
      v2f va = splat2(v0), vb = splat2(v1);
      #pragma unroll
      for(int t=0;t<16;t++) al[t] += va*wa[t];
      #pragma unroll
      for(int t=0;t<16;t++) al[t] += vb*wb[t];
    }
  }
  v2f* rl2 = (v2f*)(radlat + (size_t)e*32);
  #pragma unroll
  for(int q=0;q<16;q++) rl2[q] = al[q];
}

// ---------------- K4: init gather + out-proj + fused norm (wave/node) ----------------
__global__ __launch_bounds__(256) void k_init(const int* __restrict__ nbr,
                       const float* __restrict__ radbb, const float* __restrict__ radlat,
                       const float* __restrict__ bbf, const float* __restrict__ latn,
                       const float* __restrict__ bboutw, const float* __restrict__ latoutw,
                       const float* __restrict__ g0, const float* __restrict__ b0,
                       const float* __restrict__ g1,
                       float* __restrict__ x, float* __restrict__ xl){
  __shared__ float msgbb[4][32], msglat[4][128], xout[4][128];
  int g = threadIdx.x>>6, t = threadIdx.x&63;
  int n = blockIdx.x*4 + g;
  int t31 = t&31, t7 = t%7;
  float accL0=0.f, accL1=0.f, accB=0.f;
  for(int kk=0; kk<KNB; kk++){
    int e = n*KNB+kk;
    int j = nbr[e];
    float rl = radlat[(size_t)e*32 + t31];
    accL0 += latn[j*128+t]    * rl;
    accL1 += latn[j*128+64+t] * rl;
    if(t<28) accB += bbf[j*28+t]*radbb[(size_t)e*8 + t7];
  }
  msglat[g][t]=accL0*(1.0f/KNB); msglat[g][64+t]=accL1*(1.0f/KNB);
  if(t<28) msgbb[g][t]=accB*(1.0f/KNB);
  for(int half=0; half<2; half++){
    int e = half*64+t;
    int rrow = e>>5, c = e&31;
    float v=0.f;
    if(c<16){ for(int q=0;q<7;q++)  v += msgbb[g][rrow*7+q]*bboutw[q*16+c]; }
    else    { for(int q=0;q<32;q++) v += msglat[g][rrow*32+q]*latoutw[q*16+(c-16)]; }
    xout[g][e]=v;
    x[n*128+e]=v;
  }
  if(t<32){
    float x0=xout[g][t];
    float s=x0, s2=x0*x0;
    for(int off=16; off>0; off>>=1){ s+=__shfl_xor(s,off,32); s2+=__shfl_xor(s2,off,32); }
    float mu=s*(1.0f/32.0f), var=s2*(1.0f/32.0f)-mu*mu;
    float y0=(x0-mu)*rsqrtf(var+1e-6f)*g0[t]+b0[t];
    float v1=xout[g][32+t], v2=xout[g][64+t], v3=xout[g][96+t];
    float ss=v1*v1+v2*v2+v3*v3;
    for(int off=16; off>0; off>>=1) ss+=__shfl_xor(ss,off,32);
    float sc=rsqrtf(ss*(1.0f/96.0f)+1e-6f);
    float gg=g1[t];
    xl[n*128+t]=y0; xl[n*128+32+t]=v1*sc*gg; xl[n*128+64+t]=v2*sc*gg; xl[n*128+96+t]=v3*sc*gg;
  }
}

// ---------------- K4b: per-node hoisted halves of edge-MLP + attn-logit MLP ----------------
__global__ __launch_bounds__(256) void k_nodeprep(const float* __restrict__ x,
                       const float* __restrict__ xl,
                       const float* __restrict__ ew1, const float* __restrict__ aw1,
                       float* __restrict__ hsrc, float* __restrict__ hdst,
                       float* __restrict__ asrc, float* __restrict__ adst){
  __shared__ float sx[4][32], sl[4][32];
  int g = threadIdx.x>>6, lane = threadIdx.x&63;
  int n = blockIdx.x*4 + g;
  if(lane<32){
    if(x)   sx[g][lane] = x[n*128+lane];
    if(aw1) sl[g][lane] = xl[n*128+lane];
  }
  __syncthreads();
  if(x){
    float a0=0.f, a1=0.f;
    #pragma unroll
    for(int c=0;c<32;c++){
      float xv = sx[g][c];
      a0 += xv*ew1[(32+c)*64+lane];
      a1 += xv*ew1[(64+c)*64+lane];
    }
    hsrc[n*64+lane]=a0; hdst[n*64+lane]=a1;
  }
  if(aw1){
    int o = lane&31;
    int roff = (lane>=32)? 32 : 0;
    float a=0.f;
    #pragma unroll
    for(int c=0;c<32;c++) a += sl[g][c]*aw1[(roff+c)*32+o];
    if(lane<32) asrc[n*32+o]=a; else adst[n*32+o]=a;
  }
}

// ---------------- K5: attention logits (standalone, layer 0 only; v2f packed) ----------------
__global__ __launch_bounds__(128, 4)
void k_logits(const int* __restrict__ nbr,
              const float* __restrict__ asrc, const float* __restrict__ adst,
              const float* __restrict__ ef, const float* __restrict__ w1,
              const float* __restrict__ w2, float* __restrict__ logits){
  int e = blockIdx.x*128 + threadIdx.x;
  int n = e/KNB;
  int j = nbr[e];
  v2f h[16];
  {
    const v2f* pj = (const v2f*)(asrc + (size_t)j*32);
    const v2f* pn = (const v2f*)(adst + (size_t)n*32);
    #pragma unroll
    for(int q=0;q<16;q++) h[q] = pj[q]+pn[q];
  }
  float f[32];
  load32(f, ef + (size_t)e*32);
  #pragma unroll
  for(int c=0;c<32;c++){
    v2f fc = splat2(f[c]);
    const v2f* w = (const v2f*)(w1 + (64+c)*32);
    #pragma unroll
    for(int o=0;o<16;o++) h[o] += fc*w[o];
  }
  v2f acc[4];
  #pragma unroll
  for(int t=0;t<4;t++) acc[t]=splat2(0.f);
  #pragma unroll
  for(int o=0;o<16;o++){
    float v0 = siluf(h[o].x), v1 = siluf(h[o].y);
    const v2f* wa = (const v2f*)(w2 + (o*2)*8);
    const v2f* wb = (const v2f*)(w2 + (o*2+1)*8);
    v2f va = splat2(v0), vb = splat2(v1);
    #pragma unroll
    for(int t=0;t<4;t++) acc[t] += va*wa[t];
    #pragma unroll
    for(int t=0;t<4;t++) acc[t] += vb*wb[t];
  }
  v2f* lg2 = (v2f*)(logits + (size_t)e*8);
  #pragma unroll
  for(int q=0;q<4;q++) lg2[q] = acc[q];
}

// ---------------- K7: softmax + aggregate (float4 gather) + o_w + FFN + fused norm ----------------
// R2-proven version: wave-private LDS, NO barriers.
__global__ __launch_bounds__(256) void k_update(const int* __restrict__ nbr, const float* __restrict__ xl,
                         const float* __restrict__ logits, float* __restrict__ x,
                         float* __restrict__ xlout,
                         const float* __restrict__ vw, const float* __restrict__ ow,
                         const float* __restrict__ fw1, const float* __restrict__ fw2,
                         const float* __restrict__ fwg, const float* __restrict__ fv1,
                         const float* __restrict__ g0, const float* __restrict__ b0,
                         const float* __restrict__ g1){
  __shared__ float S_lg[4][240], S_m[4][8], S_inv[4][8];
  __shared__ float S_S[4][1024], S_agg[4][512], S_x[4][128];
  __shared__ float S_h[4][64], S_g[4][32], S_d0[4][32];
  int g = threadIdx.x>>6, t = threadIdx.x&63;
  int n = blockIdx.x*4 + g;
  for(int r=t; r<240; r+=64) S_lg[g][r] = logits[(size_t)n*240+r];
  if(t<8){
    float m=-1e30f;
    for(int kk=0;kk<KNB;kk++) m=fmaxf(m, S_lg[g][kk*8+t]);
    float s=0.f;
    for(int kk=0;kk<KNB;kk++) s += __expf(S_lg[g][kk*8+t]-m);
    S_m[g][t]=m; S_inv[g][t]=1.0f/s;
  }
  for(int r=t; r<240; r+=64){ int h=r&7; S_lg[g][r]=__expf(S_lg[g][r]-S_m[g][h])*S_inv[g][h]; }
  int hd = t>>3, i8 = t&7;
  const float4* xl4 = (const float4*)xl;
  float acc[16];
  for(int m=0;m<16;m++) acc[m]=0.f;
  for(int kk=0;kk<KNB;kk++){
    int j=nbr[n*KNB+kk];
    float a = S_lg[g][kk*8+hd];
    float4 b0v = xl4[j*32 + i8*4 + 0];
    float4 b1v = xl4[j*32 + i8*4 + 1];
    float4 b2v = xl4[j*32 + i8*4 + 2];
    float4 b3v = xl4[j*32 + i8*4 + 3];
    acc[0]+=a*b0v.x; acc[1]+=a*b0v.y; acc[2]+=a*b0v.z; acc[3]+=a*b0v.w;
    acc[4]+=a*b1v.x; acc[5]+=a*b1v.y; acc[6]+=a*b1v.z; acc[7]+=a*b1v.w;
    acc[8]+=a*b2v.x; acc[9]+=a*b2v.y; acc[10]+=a*b2v.z; acc[11]+=a*b2v.w;
    acc[12]+=a*b3v.x; acc[13]+=a*b3v.y; acc[14]+=a*b3v.z; acc[15]+=a*b3v.w;
  }
  for(int m=0;m<16;m++) S_S[g][hd*128 + i8*16 + m] = acc[m];
  for(int half=0; half<2; half++){
    int hv = half*64+t;
    int hh = hv>>4;
    float a0=0.f,a1=0.f,a2=0.f,a3=0.f;
    for(int c=0;c<32;c++){
      float w = vw[c*128+hv];
      a0 += S_S[g][hh*128 + c]*w;
      a1 += S_S[g][hh*128 + 32+c]*w;
      a2 += S_S[g][hh*128 + 64+c]*w;
      a3 += S_S[g][hh*128 + 96+c]*w;
    }
    S_agg[g][hv]=a0; S_agg[g][128+hv]=a1; S_agg[g][256+hv]=a2; S_agg[g][384+hv]=a3;
  }
  for(int half=0; half<2; half++){
    int e = half*64+t;
    int rrow = e>>5, c = e&31;
    float v = x[n*128+e];
    for(int hv=0;hv<128;hv++) v += S_agg[g][rrow*128+hv]*ow[hv*32+c];
    S_x[g][e]=v;
  }
  {
    float hs=0.f;
    for(int c=0;c<32;c++) hs += S_x[g][c]*fw1[c*64+t];
    S_h[g][t]=siluf(hs);
  }
  if(t<32){
    float gs=0.f, d0=0.f;
    for(int c=0;c<64;c++){ float hv=S_h[g][c]; gs += hv*fwg[c*32+t]; d0 += hv*fw2[c*32+t]; }
    S_g[g][t]=1.0f/(1.0f+__expf(-gs));
    S_d0[g][t]=d0;
  }
  for(int half=0; half<2; half++){
    int e = half*64+t;
    int rrow = e>>5, c = e&31;
    float xv = S_x[g][e], outv;
    if(rrow==0){ outv = xv + S_d0[g][c]; }
    else {
      float dv=0.f;
      for(int cc=0;cc<32;cc++) dv += S_x[g][rrow*32+cc]*fv1[cc*32+c];
      outv = xv + dv*S_g[g][c];
    }
    S_x[g][e]=outv;
    x[n*128+e]=outv;
  }
  if(t<32){
    float x0=S_x[g][t];
    float s=x0, s2=x0*x0;
    for(int off=16; off>0; off>>=1){ s+=__shfl_xor(s,off,32); s2+=__shfl_xor(s2,off,32); }
    float mu=s*(1.0f/32.0f), var=s2*(1.0f/32.0f)-mu*mu;
    float y0=(x0-mu)*rsqrtf(var+1e-6f)*g0[t]+b0[t];
    float v1=S_x[g][32+t], v2=S_x[g][64+t], v3=S_x[g][96+t];
    float ss=v1*v1+v2*v2+v3*v3;
    for(int off=16; off>0; off>>=1) ss+=__shfl_xor(ss,off,32);
    float sc=rsqrtf(ss*(1.0f/96.0f)+1e-6f);
    float gg=g1[t];
    xlout[n*128+t]=y0; xlout[n*128+32+t]=v1*sc*gg;
    xlout[n*128+64+t]=v2*sc*gg; xlout[n*128+96+t]=v3*sc*gg;
  }
}

// ---------------- K8: edge update + next-layer logits (layers 0..2) ----------------
// Spill-free restructure: o-dim quartered (h=16 live) and per-edge ef row staged in
// padded LDS ([128][33]: bank=(row+col)%32, 2-way across a wave = conflict-free).
// All summation orders unchanged (c asc, o asc 0..63, t asc) -> bit-identical.
__global__ __launch_bounds__(128, 4)
void k_efup(const int* __restrict__ nbr,
            const float* __restrict__ hsrc, const float* __restrict__ hdst,
            const float* __restrict__ ew1, const float* __restrict__ ew2,
            float* __restrict__ ef,
            const float* __restrict__ asrc, const float* __restrict__ adst,
            const float* __restrict__ aw1n, const float* __restrict__ aw2n,
            float* __restrict__ logits){
  __shared__ float Sf[128][33];
  int tl = threadIdx.x;
  int e = blockIdx.x*128 + tl;
  int n = e/KNB;
  int j = nbr[e];
  // stage this edge's ef row into LDS (b32 writes, conflict-free)
  {
    const float4* s4 = (const float4*)(ef + (size_t)e*32);
    #pragma unroll
    for(int q=0;q<8;q++){
      float4 v = s4[q];
      Sf[tl][q*4+0]=v.x; Sf[tl][q*4+1]=v.y; Sf[tl][q*4+2]=v.z; Sf[tl][q*4+3]=v.w;
    }
  }
  v2f acc[16];
  #pragma unroll
  for(int t=0;t<16;t++) acc[t]=splat2(0.f);
  #pragma unroll
  for(int oq=0; oq<4; oq++){
    v2f h[8];
    {
      const float4* pj = (const float4*)(hsrc + (size_t)j*64 + oq*16);
      const float4* pn = (const float4*)(hdst + (size_t)n*64 + oq*16);
      #pragma unroll
      for(int q=0;q<4;q++){
        float4 a=pj[q], b=pn[q];
        h[2*q]   = (v2f){a.x+b.x, a.y+b.y};
        h[2*q+1] = (v2f){a.z+b.z, a.w+b.w};
      }
    }
    #pragma unroll
    for(int c=0;c<32;c++){
      v2f fc = splat2(Sf[tl][c]);
      const v2f* w = (const v2f*)(ew1 + c*64 + oq*16);
      #pragma unroll
      for(int o=0;o<8;o++) h[o] += fc*w[o];
    }
    #pragma unroll
    for(int o=0;o<8;o++){
      float v0 = siluf(h[o].x), v1 = siluf(h[o].y);
      const v2f* wa = (const v2f*)(ew2 + (oq*16+o*2)*32);
      const v2f* wb = (const v2f*)(ew2 + (oq*16+o*2+1)*32);
      v2f va = splat2(v0), vb = splat2(v1);
      #pragma unroll
      for(int t=0;t<16;t++) acc[t] += va*wa[t];
      #pragma unroll
      for(int t=0;t<16;t++) acc[t] += vb*wb[t];
    }
  }
  // residual: fn = f_old + acc; write to global and back into LDS (for logits)
  {
    float4* e4 = (float4*)(ef + (size_t)e*32);
    #pragma unroll
    for(int q=0;q<8;q++){
      float f0 = Sf[tl][q*4+0] + acc[2*q].x;
      float f1 = Sf[tl][q*4+1] + acc[2*q].y;
      float f2 = Sf[tl][q*4+2] + acc[2*q+1].x;
      float f3 = Sf[tl][q*4+3] + acc[2*q+1].y;
      e4[q] = make_float4(f0,f1,f2,f3);
      Sf[tl][q*4+0]=f0; Sf[tl][q*4+1]=f1; Sf[tl][q*4+2]=f2; Sf[tl][q*4+3]=f3;
    }
  }
  // next-layer logits on (asrc[j]+adst[n], new ef)
  v2f h2[16];
  {
    const v2f* pj = (const v2f*)(asrc + (size_t)j*32);
    const v2f* pn = (const v2f*)(adst + (size_t)n*32);
    #pragma unroll
    for(int q=0;q<16;q++) h2[q] = pj[q]+pn[q];
  }
  #pragma unroll
  for(int c=0;c<32;c++){
    v2f fc = splat2(Sf[tl][c]);
    const v2f* w = (const v2f*)(aw1n + (64+c)*32);
    #pragma unroll
    for(int o=0;o<16;o++) h2[o] += fc*w[o];
  }
  v2f a8[4];
  #pragma unroll
  for(int t=0;t<4;t++) a8[t]=splat2(0.f);
  #pragma unroll
  for(int o=0;o<16;o++){
    float v0 = siluf(h2[o].x), v1 = siluf(h2[o].y);
    const v2f* wa = (const v2f*)(aw2n + (o*2)*8);
    const v2f* wb = (const v2f*)(aw2n + (o*2+1)*8);
    v2f va = splat2(v0), vb = splat2(v1);
    #pragma unroll
    for(int t=0;t<4;t++) a8[t] += va*wa[t];
    #pragma unroll
    for(int t=0;t<4;t++) a8[t] += vb*wb[t];
  }
  v2f* lg2 = (v2f*)(logits + (size_t)e*8);
  #pragma unroll
  for(int q=0;q<4;q++) lg2[q] = a8[q];
}

// ---------------- K8b: layer-3 edge update + out radial MLP fused; writes orad IN-PLACE over ef ----------------
__global__ __launch_bounds__(128, 4)
void k_efup_orad(const int* __restrict__ nbr,
                 const float* __restrict__ hsrc, const float* __restrict__ hdst,
                 const float* __restrict__ ew1, const float* __restrict__ ew2,
                 float* __restrict__ ef,
                 const float* __restrict__ orw1, const float* __restrict__ orw2){
  int e = blockIdx.x*128 + threadIdx.x;
  int n = e/KNB;
  int j = nbr[e];
  float f[32];
  load32(f, ef + (size_t)e*32);
  v2f acc[16];
  #pragma unroll
  for(int t=0;t<16;t++) acc[t]=splat2(0.f);
  #pragma unroll
  for(int half=0; half<2; half++){
    v2f h[16];
    {
      const v2f* pj = (const v2f*)(hsrc + (size_t)j*64 + half*32);
      const v2f* pn = (const v2f*)(hdst + (size_t)n*64 + half*32);
      #pragma unroll
      for(int q=0;q<16;q++) h[q] = pj[q]+pn[q];
    }
    #pragma unroll
    for(int c=0;c<32;c++){
      v2f fc = splat2(f[c]);
      const v2f* w = (const v2f*)(ew1 + c*64 + half*32);
      #pragma unroll
      for(int o=0;o<16;o++) h[o] += fc*w[o];
    }
    #pragma unroll
    for(int o=0;o<16;o++){
      float v0 = siluf(h[o].x), v1 = siluf(h[o].y);
      const v2f* wa = (const v2f*)(ew2 + (half*32+o*2)*32);
      const v2f* wb = (const v2f*)(ew2 + (half*32+o*2+1)*32);
      v2f va = splat2(v0), vb = splat2(v1);
      #pragma unroll
      for(int t=0;t<16;t++) acc[t] += va*wa[t];
      #pragma unroll
      for(int t=0;t<16;t++) acc[t] += vb*wb[t];
    }
  }
  // new ef (layer 3) kept in registers only — its sole consumer is the orad MLP below
  #pragma unroll
  for(int t=0;t<16;t++){ f[2*t] += acc[t].x; f[2*t+1] += acc[t].y; }
  // out radial MLP: 32->64(silu)->32 on new ef
  v2f oa[16];
  #pragma unroll
  for(int t=0;t<16;t++) oa[t]=splat2(0.f);
  #pragma unroll
  for(int half=0; half<2; half++){
    v2f h[16];
    #pragma unroll
    for(int o=0;o<16;o++) h[o]=splat2(0.f);
    #pragma unroll
    for(int c=0;c<32;c++){
      v2f fc = splat2(f[c]);
      const v2f* w = (const v2f*)(orw1 + c*64 + half*32);
      #pragma unroll
      for(int o=0;o<16;o++) h[o] += fc*w[o];
    }
    #pragma unroll
    for(int o=0;o<16;o++){
      float v0 = siluf(h[o].x), v1 = siluf(h[o].y);
      const v2f* wa = (const v2f*)(orw2 + (half*32+o*2)*32);
      const v2f* wb = (const v2f*)(orw2 + (half*32+o*2+1)*32);
      v2f va = splat2(v0), vb = splat2(v1);
      #pragma unroll
      for(int t=0;t<16;t++) oa[t] += va*wa[t];
      #pragma unroll
      for(int t=0;t<16;t++) oa[t] += vb*wb[t];
    }
  }
  // in-place: thread e owns slot e of ef; write orad there (ef dead afterwards)
  v2f* r2 = (v2f*)(ef + (size_t)e*32);
  #pragma unroll
  for(int q=0;q<16;q++) r2[q] = oa[q];
}

// ---------------- K9: out gather + projection + fused seq head ----------------
__global__ __launch_bounds__(256) void k_out(const int* __restrict__ nbr, const float* __restrict__ orad,
                      const float* __restrict__ x,
                      const float* __restrict__ outw,
                      const float* __restrict__ sw1, const float* __restrict__ sb1,
                      const float* __restrict__ sw2, const float* __restrict__ sb2,
                      const float* __restrict__ sw3, const float* __restrict__ sb3,
                      float* __restrict__ out, float* __restrict__ outseq){
  __shared__ float msg[4][128];
  __shared__ float h1[4][64], h2[4][32], lgs[4][20];
  int g = threadIdx.x>>6, t = threadIdx.x&63;
  int n = blockIdx.x*4 + g;
  int t31 = t&31;
  float acc0=0.f, acc1=0.f;
  for(int kk=0;kk<KNB;kk++){
    int e=n*KNB+kk;
    int j=nbr[e];
    float rl = orad[(size_t)e*32 + t31];
    acc0 += x[j*128+t]*rl;
    acc1 += x[j*128+64+t]*rl;
  }
  msg[g][t]=acc0*(1.0f/KNB); msg[g][64+t]=acc1*(1.0f/KNB);
  for(int o=t;o<91;o+=64){
    for(int rrow=1;rrow<4;rrow++){
      float s=0.f;
      for(int c=0;c<32;c++) s += msg[g][rrow*32+c]*outw[c*91+o];
      out[(size_t)n*273 + o*3 + (rrow-1)] = s;
    }
  }
  {
    float s=0.f;
    for(int c=0;c<32;c++) s += x[n*128+c]*sw1[c*64+t];
    h1[g][t]=fmaxf(s+sb1[t],0.f);
  }
  if(t<32){
    float s=0.f;
    for(int c=0;c<64;c++) s += h1[g][c]*sw2[c*32+t];
    h2[g][t]=fmaxf(s+sb2[t],0.f);
  }
  if(t<20){
    float s=0.f;
    for(int c=0;c<32;c++) s += h2[g][c]*sw3[c*20+t];
    lgs[g][t]=s+sb3[t];
  }
  if(t<20){
    float m=-1e30f;
    for(int c=0;c<20;c++) m=fmaxf(m,lgs[g][c]);
    float se=0.f;
    for(int c=0;c<20;c++) se += __expf(lgs[g][c]-m);
    outseq[(size_t)n*20+t]=lgs[g][t]-m-logf(se);
  }
}

extern "C" void kernel_launch(void* const* d_in, const int* in_sizes, int n_in,
                              void* d_out, int out_size, void* d_ws, size_t ws_size,
                              hipStream_t stream) {
  const float* bb      = (const float*)d_in[0];
  const float* latent  = (const float*)d_in[1];
  const float* ln_g0   = (const float*)d_in[2];
  const float* ln_b0   = (const float*)d_in[3];
  const float* ln_g1   = (const float*)d_in[4];
  const float* bbw1    = (const float*)d_in[5];
  const float* bbw2    = (const float*)d_in[6];
  const float* bboutw  = (const float*)d_in[7];
  const float* latw1   = (const float*)d_in[8];
  const float* latw2   = (const float*)d_in[9];
  const float* latoutw = (const float*)d_in[10];
  const float* tg0     = (const float*)d_in[11];
  const float* tb0     = (const float*)d_in[12];
  const float* tg1     = (const float*)d_in[13];
  const float* aw1     = (const float*)d_in[14];
  const float* aw2     = (const float*)d_in[15];
  const float* vw      = (const float*)d_in[16];
  const float* ow      = (const float*)d_in[17];
  const float* fw1     = (const float*)d_in[18];
  const float* fw2     = (const float*)d_in[19];
  const float* fwg     = (const float*)d_in[20];
  const float* fv1     = (const float*)d_in[21];
  const float* ew1     = (const float*)d_in[22];
  const float* ew2     = (const float*)d_in[23];
  const float* orw1    = (const float*)d_in[24];
  const float* orw2    = (const float*)d_in[25];
  const float* outw    = (const float*)d_in[26];
  const float* sw1     = (const float*)d_in[27];
  const float* sb1     = (const float*)d_in[28];
  const float* sw2     = (const float*)d_in[29];
  const float* sb2     = (const float*)d_in[30];
  const float* sw3     = (const float*)d_in[31];
  const float* sb3     = (const float*)d_in[32];
  float* outp = (float*)d_out;

  // workspace layout (radbb overlays logits; radlat + nodeprep arrays overlay edgescratch;
  // tbl overlays xbuf (dead until k_init); orad written in-place over ef by k_efup_orad)
  int*    nbr    = (int*)d_ws;
  float*  ef     = (float*)((char*)d_ws + 1024*1024);
  float*  xbuf   = ef   + (size_t)NEDGE*32;
  float*  xlA    = xbuf + (size_t)NRES*128;
  float*  xlB    = xlA  + (size_t)NRES*128;
  float*  bbf    = xlB  + (size_t)NRES*128;
  float*  logits = bbf  + (size_t)NRES*28;
  float4* ca     = (float4*)(logits + (size_t)NEDGE*8);
  float*  edgescratch = (float*)(ca + NRES);     // NEDGE*32 floats
  float*  radbb  = logits;                       // NEDGE*8, dead before first k_logits
  float*  radlat = edgescratch;                  // NEDGE*32, dead after k_init
  float*  tbl    = xbuf;                         // 4096*16 floats, xbuf dead until k_init
  // per-node hoisted arrays: live only between k_init and k_efup_orad (radlat dead window)
  float*  hsrc   = edgescratch;                              // NRES*64
  float*  hdst   = edgescratch + (size_t)NRES*64;            // NRES*64
  float*  asrc   = edgescratch + (size_t)NRES*128;           // NRES*32
  float*  adst   = edgescratch + (size_t)NRES*128 + (size_t)NRES*32; // NRES*32

  k_bbfeat  <<<NRES/256, 256, 0, stream>>>(bb, bbf, ca);
  k_knn     <<<NRES/4,   256, 0, stream>>>(ca, nbr);
  k_tbl     <<<4096*8/256, 256, 0, stream>>>(tbl);
  k_edgefeat<<<NEDGE/256, 256, 0, stream>>>(ca, nbr, tbl, ef);
  k_norm    <<<NRES*32/256, 256, 0, stream>>>(latent, xlA, ln_g0, ln_b0, ln_g1);
  k_rad     <<<NEDGE/128, 128, 0, stream>>>(ef, bbw1, bbw2, latw1, latw2, radbb, radlat);
  k_init    <<<NRES/4, 256, 0, stream>>>(nbr, radbb, radlat, bbf, xlA,
                                         bboutw, latoutw,
                                         tg0, tb0, tg1,
                                         xbuf, xlB);
  // layer-0 logits: hoist xl halves, then per-edge ef part
  k_nodeprep<<<NRES/4, 256, 0, stream>>>(nullptr, xlB, ew1, aw1, hsrc, hdst, asrc, adst);
  k_logits  <<<NEDGE/128, 128, 0, stream>>>(nbr, asrc, adst, ef, aw1, aw2, logits);
  for(int l=0;l<4;l++){
    const float* xl_in  = (l&1) ? xlA : xlB;
    float*       xl_out = (l&1) ? xlB : xlA;
    int ln = (l+1<4) ? (l+1) : 3;
    k_update <<<NRES/4, 256, 0, stream>>>(nbr, xl_in, logits, xbuf, xl_out,
                                          vw+l*32*128, ow+l*128*32,
                                          fw1+l*32*64, fw2+l*64*32,
                                          fwg+l*64*32, fv1+l*32*32,
                                          tg0+ln*32, tb0+ln*32, tg1+ln*32);
    if(l<3){
      k_nodeprep<<<NRES/4, 256, 0, stream>>>(xbuf, xl_out, ew1+l*96*64, aw1+(l+1)*96*32,
                                             hsrc, hdst, asrc, adst);
      k_efup<<<NEDGE/128, 128, 0, stream>>>(nbr, hsrc, hdst,
                                            ew1+l*96*64, ew2+l*64*32, ef,
                                            asrc, adst,
                                            aw1+(l+1)*96*32, aw2+(l+1)*32*8, logits);
    } else {
      k_nodeprep<<<NRES/4, 256, 0, stream>>>(xbuf, xl_out, ew1+l*96*64, nullptr,
                                             hsrc, hdst, asrc, adst);
      k_efup_orad<<<NEDGE/128, 128, 0, stream>>>(nbr, hsrc, hdst,
                                                 ew1+l*96*64, ew2+l*64*32, ef,
                                                 orw1, orw2);
    }
  }
  k_out <<<NRES/4, 256, 0, stream>>>(nbr, ef /*orad in-place*/, xbuf, outw,
                                     sw1, sb1, sw2, sb2, sw3, sb3,
                                     outp, outp + (size_t)NRES*273);
}

// Round 8
// 1106.407 us; speedup vs baseline: 1.4316x; 1.0302x over previous
//
#include <hip/hip_runtime.h>
#include <math.h>

#define NRES 8192
#define NPER 2048
#define KNB  30
#define NEDGE (NRES*KNB)

typedef float v2f __attribute__((ext_vector_type(2)));

__device__ __forceinline__ float siluf(float x){ return x / (1.0f + __expf(-x)); }
__device__ __forceinline__ v2f splat2(float a){ v2f r; r.x=a; r.y=a; return r; }

// ---------------- K0: backbone features + ca pack ----------------
__global__ void k_bbfeat(const float* __restrict__ bb, float* __restrict__ bbf,
                         float4* __restrict__ ca){
  int n = blockIdx.x*256 + threadIdx.x;
  if(n >= NRES) return;
  const float* r = bb + n*12;
  float cax=r[3], cay=r[4], caz=r[5];
  ca[n] = make_float4(cax,cay,caz, cax*cax+cay*cay+caz*caz);
  float vx[7],vy[7],vz[7];
  for(int a=0;a<4;a++){ vx[a]=r[a*3]-cax; vy[a]=r[a*3+1]-cay; vz[a]=r[a*3+2]-caz; }
  if(n<NRES-1){
    float dx=bb[(n+1)*12+3]-cax, dy=bb[(n+1)*12+4]-cay, dz=bb[(n+1)*12+5]-caz;
    float s=rsqrtf(dx*dx+dy*dy+dz*dz+1e-8f);
    vx[4]=dx*s; vy[4]=dy*s; vz[4]=dz*s;
  } else { vx[4]=0.f; vy[4]=0.f; vz[4]=0.f; }
  if(n>0){
    float dx=bb[(n-1)*12+3]-cax, dy=bb[(n-1)*12+4]-cay, dz=bb[(n-1)*12+5]-caz;
    float s=rsqrtf(dx*dx+dy*dy+dz*dz+1e-8f);
    vx[5]=dx*s; vy[5]=dy*s; vz[5]=dz*s;
  } else { vx[5]=0.f; vy[5]=0.f; vz[5]=0.f; }
  {
    float bx=cax-r[0], by=cay-r[1], bz=caz-r[2];
    float cx=r[6]-cax, cy=r[7]-cay, cz=r[8]-caz;
    float axx=by*cz-bz*cy, ayy=bz*cx-bx*cz, azz=bx*cy-by*cx;
    vx[6]=-0.58273431f*axx+0.56802827f*bx-0.54067466f*cx;
    vy[6]=-0.58273431f*ayy+0.56802827f*by-0.54067466f*cy;
    vz[6]=-0.58273431f*azz+0.56802827f*bz-0.54067466f*cz;
  }
  float cD[3], sD[3];
  for(int t=0;t<3;t++){
    cD[t]=1.0f; sD[t]=0.0f;
    int f=3*n+t-1;
    if(f>=0 && f<3*NRES-3){
      float X[4][3];
      for(int q=0;q<4;q++){
        int m=f+q, rr=m/3, aa=m-rr*3;
        X[q][0]=bb[rr*12+aa*3]; X[q][1]=bb[rr*12+aa*3+1]; X[q][2]=bb[rr*12+aa*3+2];
      }
      float u2x=X[1][0]-X[0][0], u2y=X[1][1]-X[0][1], u2z=X[1][2]-X[0][2];
      float u1x=X[2][0]-X[1][0], u1y=X[2][1]-X[1][1], u1z=X[2][2]-X[1][2];
      float u0x=X[3][0]-X[2][0], u0y=X[3][1]-X[2][1], u0z=X[3][2]-X[2][2];
      float s2=rsqrtf(u2x*u2x+u2y*u2y+u2z*u2z+1e-8f); u2x*=s2; u2y*=s2; u2z*=s2;
      float s1=rsqrtf(u1x*u1x+u1y*u1y+u1z*u1z+1e-8f); u1x*=s1; u1y*=s1; u1z*=s1;
      float s0=rsqrtf(u0x*u0x+u0y*u0y+u0z*u0z+1e-8f); u0x*=s0; u0y*=s0; u0z*=s0;
      float n2x=u2y*u1z-u2z*u1y, n2y=u2z*u1x-u2x*u1z, n2z=u2x*u1y-u2y*u1x;
      float nn2=rsqrtf(n2x*n2x+n2y*n2y+n2z*n2z+1e-8f); n2x*=nn2; n2y*=nn2; n2z*=nn2;
      float n1x=u1y*u0z-u1z*u0y, n1y=u1z*u0x-u1x*u0z, n1z=u1x*u0y-u1y*u0x;
      float nn1=rsqrtf(n1x*n1x+n1y*n1y+n1z*n1z+1e-8f); n1x*=nn1; n1y*=nn1; n1z*=nn1;
      float dotn = n2x*n1x+n2y*n1y+n2z*n1z;
      float cosD = fminf(fmaxf(dotn, -1.0f+1e-6f), 1.0f-1e-6f);
      float sg = u2x*n1x+u2y*n1y+u2z*n1z;
      if(sg==0.0f){ cD[t]=1.0f; sD[t]=0.0f; }
      else {
        float sgn = (sg>0.0f)?1.0f:-1.0f;
        cD[t]=cosD;
        sD[t]=sgn*sqrtf(fmaxf(1.0f-cosD*cosD,0.0f));
      }
    }
  }
  float* o = bbf + n*28;
  o[0]=cD[0]; o[1]=cD[1]; o[2]=cD[2]; o[3]=sD[0]; o[4]=sD[1]; o[5]=sD[2]; o[6]=0.f;
  for(int c=0;c<7;c++){ o[7+c]=vx[c]; o[14+c]=vy[c]; o[21+c]=vz[c]; }
}

// helper: per-lane extraction of the next-smallest unconsumed value as packed u64 key.
__device__ __forceinline__ unsigned long long knn_extract(const float* __restrict__ vals,
                                                          unsigned &mask, int lane){
  float bm=INFINITY; int ba=0;
  #pragma unroll
  for(int t=0;t<32;t++){
    if(!((mask>>t)&1u) && vals[t]<bm){ bm=vals[t]; ba=t; }
  }
  mask |= 1u<<ba;
  unsigned ub = __float_as_uint(bm);
  ub ^= (ub & 0x80000000u) ? 0xFFFFFFFFu : 0x80000000u;
  return ((unsigned long long)ub<<32) | (unsigned)(ba*64+lane);
}

// ---------------- K1: kNN — wave/query, u64-key tournament with per-lane cached top-4 ----------------
__global__ __launch_bounds__(256) void k_knn(const float4* __restrict__ ca, int* __restrict__ nbr){
  __shared__ float sx[NPER], sy[NPER], sz[NPER], sq[NPER];
  int wave = threadIdx.x>>6;
  int lane = threadIdx.x&63;
  int i = blockIdx.x*4 + wave;
  int batch = i / NPER;
  int base = batch*NPER;
  for(int t=threadIdx.x; t<NPER; t+=256){
    float4 c = ca[base+t];
    sx[t]=c.x; sy[t]=c.y; sz[t]=c.z; sq[t]=c.w;
  }
  __syncthreads();
  int il = i - base;
  float xi=sx[il], yi=sy[il], zi=sz[il], si=sq[il];
  float vals[32];
  #pragma unroll
  for(int t=0;t<32;t++){
    int j = t*64 + lane;
    float d2 = si + sq[j] - 2.0f*(xi*sx[j]+yi*sy[j]+zi*sz[j]);
    if(j==il) d2 = 1e30f;
    vals[t]=d2;
  }
  unsigned mask = 0;
  unsigned long long s0 = knn_extract(vals, mask, lane);
  unsigned long long s1 = knn_extract(vals, mask, lane);
  unsigned long long s2 = knn_extract(vals, mask, lane);
  unsigned long long s3 = knn_extract(vals, mask, lane);
  const unsigned long long EMPTY = ~0ull;
  for(int it=0; it<KNB; it++){
    unsigned long long m = s0;
    #pragma unroll
    for(int off=32; off>0; off>>=1){
      unsigned long long o = __shfl_xor(m, off, 64);
      m = (o<m) ? o : m;
    }
    if(lane==0) nbr[i*KNB+it] = base + (int)(m & 0x7FFull);
    if((int)(m & 63ull) == lane){
      s0=s1; s1=s2; s2=s3; s3=EMPTY;
      if(s0==EMPTY) s0 = knn_extract(vals, mask, lane);  // rare refill
    }
  }
}

// ---------------- K2a: trig table for positional embedding ----------------
__global__ void k_tbl(float* __restrict__ tbl){
  int i = blockIdx.x*256 + threadIdx.x;   // 4096*8 items
  int d = i>>3, m = i&7;
  float freq = __expf(-1.1512925465f*(float)m);  // 10000^(-m/8)
  float ang = (float)(d-2048)*freq;
  tbl[d*16+m]   = cosf(ang);
  tbl[d*16+8+m] = sinf(ang);
}

// ---------------- K2: edge features ef (N,k,32) = [rbf16, cos8, sin8] ----------------
__global__ void k_edgefeat(const float4* __restrict__ ca, const int* __restrict__ nbr,
                           const float* __restrict__ tbl, float* __restrict__ ef){
  int e = blockIdx.x*256 + threadIdx.x;
  if(e >= NEDGE) return;
  int n = e/KNB;
  int j = nbr[e];
  float4 cn = ca[n], cj = ca[j];
  float dx=cn.x-cj.x, dy=cn.y-cj.y, dz=cn.z-cj.z;
  float dist = sqrtf(dx*dx+dy*dy+dz*dz + 1e-12f);
  float f[32];
  #pragma unroll
  for(int m=0;m<16;m++){
    float mu = (20.0f/15.0f)*(float)m;
    float t = (dist-mu)*(1.0f/1.25f);
    f[m] = __expf(-t*t);
  }
  {
    const float4* t4 = (const float4*)(tbl + (size_t)(j - n + 2048)*16);
    float4 c0=t4[0], c1=t4[1], s0=t4[2], s1=t4[3];
    f[16]=c0.x; f[17]=c0.y; f[18]=c0.z; f[19]=c0.w;
    f[20]=c1.x; f[21]=c1.y; f[22]=c1.z; f[23]=c1.w;
    f[24]=s0.x; f[25]=s0.y; f[26]=s0.z; f[27]=s0.w;
    f[28]=s1.x; f[29]=s1.y; f[30]=s1.z; f[31]=s1.w;
  }
  float4* o4 = (float4*)(ef + (size_t)e*32);
  #pragma unroll
  for(int q=0;q<8;q++) o4[q] = make_float4(f[q*4],f[q*4+1],f[q*4+2],f[q*4+3]);
}

// ---------------- K3: norm_so3 (latent only) ----------------
__global__ void k_norm(const float* __restrict__ in, float* __restrict__ out,
                       const float* __restrict__ g0, const float* __restrict__ b0,
                       const float* __restrict__ g1){
  int tid = blockIdx.x*256 + threadIdx.x;
  int n = tid >> 5, lane = tid & 31;
  if(n >= NRES) return;
  const float* xn = in + n*128;
  float x0 = xn[lane];
  float s = x0, s2 = x0*x0;
  for(int off=16; off>0; off>>=1){ s += __shfl_xor(s, off, 32); s2 += __shfl_xor(s2, off, 32); }
  float mu = s*(1.0f/32.0f);
  float var = s2*(1.0f/32.0f) - mu*mu;
  float y0 = (x0-mu)*rsqrtf(var+1e-6f)*g0[lane] + b0[lane];
  float v1 = xn[32+lane], v2 = xn[64+lane], v3 = xn[96+lane];
  float ss = v1*v1+v2*v2+v3*v3;
  for(int off=16; off>0; off>>=1){ ss += __shfl_xor(ss, off, 32); }
  float sc = rsqrtf(ss*(1.0f/96.0f) + 1e-6f);
  float g = g1[lane];
  out[n*128+lane]     = y0;
  out[n*128+32+lane]  = v1*sc*g;
  out[n*128+64+lane]  = v2*sc*g;
  out[n*128+96+lane]  = v3*sc*g;
}

// helper: load 32 floats into a register array (callers index with constants only)
__device__ __forceinline__ void load32(float* __restrict__ f, const float* __restrict__ src){
  const float4* s4 = (const float4*)src;
  #pragma unroll
  for(int q=0;q<8;q++){
    float4 v = s4[q];
    f[q*4+0]=v.x; f[q*4+1]=v.y; f[q*4+2]=v.z; f[q*4+3]=v.w;
  }
}

// ---------------- K4a: init radial MLPs, lane-per-edge, v2f packed FMA ----------------
__global__ __launch_bounds__(128, 4)
void k_rad(const float* __restrict__ ef,
           const float* __restrict__ bbw1, const float* __restrict__ bbw2,
           const float* __restrict__ latw1, const float* __restrict__ latw2,
           float* __restrict__ radbb, float* __restrict__ radlat){
  int e = blockIdx.x*128 + threadIdx.x;
  float f[32];
  load32(f, ef + (size_t)e*32);
  // ---- bb branch: 32->64(silu)->7, o in two halves of 32 (same FP order) ----
  float ab[7];
  #pragma unroll
  for(int t=0;t<7;t++) ab[t]=0.f;
  #pragma unroll
  for(int half=0; half<2; half++){
    v2f h[16];
    #pragma unroll
    for(int o=0;o<16;o++) h[o]=splat2(0.f);
    #pragma unroll
    for(int c=0;c<32;c++){
      v2f fc = splat2(f[c]);
      const v2f* w = (const v2f*)(bbw1 + c*64 + half*32);
      #pragma unroll
      for(int o=0;o<16;o++) h[o] += fc*w[o];
    }
    #pragma unroll
    for(int o=0;o<16;o++){
      float v0 = siluf(h[o].x), v1 = siluf(h[o].y);
      const float* wa = bbw2 + (half*32+o*2)*7;
      const float* wb = bbw2 + (half*32+o*2+1)*7;
      #pragma unroll
      for(int t=0;t<7;t++) ab[t] += v0*wa[t];
      #pragma unroll
      for(int t=0;t<7;t++) ab[t] += v1*wb[t];
    }
  }
  {
    float4* rb4 = (float4*)(radbb + (size_t)e*8);
    rb4[0] = make_float4(ab[0],ab[1],ab[2],ab[3]);
    rb4[1] = make_float4(ab[4],ab[5],ab[6],0.f);
  }
  // ---- lat branch: 32->64(silu)->32, o-halved, v2f ----
  v2f al[16];
  #pragma unroll
  for(int t=0;t<16;t++) al[t]=splat2(0.f);
  #pragma unroll
  for(int half=0; half<2; half++){
    v2f h[16];
    #pragma unroll
    for(int o=0;o<16;o++) h[o]=splat2(0.f);
    #pragma unroll
    for(int c=0;c<32;c++){
      v2f fc = splat2(f[c]);
      const v2f* w = (const v2f*)(latw1 + c*64 + half*32);
      #pragma unroll
      for(int o=0;o<16;o++) h[o] += fc*w[o];
    }
    #pragma unroll
    for(int o=0;o<16;o++){
      float v0 = siluf(h[o].x), v1 = siluf(h[o].y);
      const v2f* wa = (const v2f*)(latw2 + (half*32+o*2)*32);
      const v2f* wb = (const v2f*)(latw2 + (half*32+o*2+1)*32);
      v2f va = splat2(v0), vb = splat2(v1);
      #pragma unroll
      for(int t=0;t<16;t++) al[t] += va*wa[t];
      #pragma unroll
      for(int t=0;t<16;t++) al[t] += vb*wb[t];
    }
  }
  v2f* rl2 = (v2f*)(radlat + (size_t)e*32);
  #pragma unroll
  for(int q=0;q<16;q++) rl2[q] = al[q];
}

// ---------------- K4: init gather + out-proj + fused norm (wave/node) ----------------
__global__ __launch_bounds__(256) void k_init(const int* __restrict__ nbr,
                       const float* __restrict__ radbb, const float* __restrict__ radlat,
                       const float* __restrict__ bbf, const float* __restrict__ latn,
                       const float* __restrict__ bboutw, const float* __restrict__ latoutw,
                       const float* __restrict__ g0, const float* __restrict__ b0,
                       const float* __restrict__ g1,
                       float* __restrict__ x, float* __restrict__ xl){
  __shared__ float msgbb[4][32], msglat[4][128], xout[4][128];
  int g = threadIdx.x>>6, t = threadIdx.x&63;
  int n = blockIdx.x*4 + g;
  int t31 = t&31, t7 = t%7;
  float accL0=0.f, accL1=0.f, accB=0.f;
  for(int kk=0; kk<KNB; kk++){
    int e = n*KNB+kk;
    int j = nbr[e];
    float rl = radlat[(size_t)e*32 + t31];
    accL0 += latn[j*128+t]    * rl;
    accL1 += latn[j*128+64+t] * rl;
    if(t<28) accB += bbf[j*28+t]*radbb[(size_t)e*8 + t7];
  }
  msglat[g][t]=accL0*(1.0f/KNB); msglat[g][64+t]=accL1*(1.0f/KNB);
  if(t<28) msgbb[g][t]=accB*(1.0f/KNB);
  for(int half=0; half<2; half++){
    int e = half*64+t;
    int rrow = e>>5, c = e&31;
    float v=0.f;
    if(c<16){ for(int q=0;q<7;q++)  v += msgbb[g][rrow*7+q]*bboutw[q*16+c]; }
    else    { for(int q=0;q<32;q++) v += msglat[g][rrow*32+q]*latoutw[q*16+(c-16)]; }
    xout[g][e]=v;
    x[n*128+e]=v;
  }
  if(t<32){
    float x0=xout[g][t];
    float s=x0, s2=x0*x0;
    for(int off=16; off>0; off>>=1){ s+=__shfl_xor(s,off,32); s2+=__shfl_xor(s2,off,32); }
    float mu=s*(1.0f/32.0f), var=s2*(1.0f/32.0f)-mu*mu;
    float y0=(x0-mu)*rsqrtf(var+1e-6f)*g0[t]+b0[t];
    float v1=xout[g][32+t], v2=xout[g][64+t], v3=xout[g][96+t];
    float ss=v1*v1+v2*v2+v3*v3;
    for(int off=16; off>0; off>>=1) ss+=__shfl_xor(ss,off,32);
    float sc=rsqrtf(ss*(1.0f/96.0f)+1e-6f);
    float gg=g1[t];
    xl[n*128+t]=y0; xl[n*128+32+t]=v1*sc*gg; xl[n*128+64+t]=v2*sc*gg; xl[n*128+96+t]=v3*sc*gg;
  }
}

// ---------------- K4b: per-node hoisted halves of edge-MLP + attn-logit MLP ----------------
__global__ __launch_bounds__(256) void k_nodeprep(const float* __restrict__ x,
                       const float* __restrict__ xl,
                       const float* __restrict__ ew1, const float* __restrict__ aw1,
                       float* __restrict__ hsrc, float* __restrict__ hdst,
                       float* __restrict__ asrc, float* __restrict__ adst){
  __shared__ float sx[4][32], sl[4][32];
  int g = threadIdx.x>>6, lane = threadIdx.x&63;
  int n = blockIdx.x*4 + g;
  if(lane<32){
    if(x)   sx[g][lane] = x[n*128+lane];
    if(aw1) sl[g][lane] = xl[n*128+lane];
  }
  __syncthreads();
  if(x){
    float a0=0.f, a1=0.f;
    #pragma unroll
    for(int c=0;c<32;c++){
      float xv = sx[g][c];
      a0 += xv*ew1[(32+c)*64+lane];
      a1 += xv*ew1[(64+c)*64+lane];
    }
    hsrc[n*64+lane]=a0; hdst[n*64+lane]=a1;
  }
  if(aw1){
    int o = lane&31;
    int roff = (lane>=32)? 32 : 0;
    float a=0.f;
    #pragma unroll
    for(int c=0;c<32;c++) a += sl[g][c]*aw1[(roff+c)*32+o];
    if(lane<32) asrc[n*32+o]=a; else adst[n*32+o]=a;
  }
}

// ---------------- K5: attention logits (standalone, layer 0 only; v2f packed) ----------------
__global__ __launch_bounds__(128, 4)
void k_logits(const int* __restrict__ nbr,
              const float* __restrict__ asrc, const float* __restrict__ adst,
              const float* __restrict__ ef, const float* __restrict__ w1,
              const float* __restrict__ w2, float* __restrict__ logits){
  int e = blockIdx.x*128 + threadIdx.x;
  int n = e/KNB;
  int j = nbr[e];
  v2f h[16];
  {
    const v2f* pj = (const v2f*)(asrc + (size_t)j*32);
    const v2f* pn = (const v2f*)(adst + (size_t)n*32);
    #pragma unroll
    for(int q=0;q<16;q++) h[q] = pj[q]+pn[q];
  }
  float f[32];
  load32(f, ef + (size_t)e*32);
  #pragma unroll
  for(int c=0;c<32;c++){
    v2f fc = splat2(f[c]);
    const v2f* w = (const v2f*)(w1 + (64+c)*32);
    #pragma unroll
    for(int o=0;o<16;o++) h[o] += fc*w[o];
  }
  v2f acc[4];
  #pragma unroll
  for(int t=0;t<4;t++) acc[t]=splat2(0.f);
  #pragma unroll
  for(int o=0;o<16;o++){
    float v0 = siluf(h[o].x), v1 = siluf(h[o].y);
    const v2f* wa = (const v2f*)(w2 + (o*2)*8);
    const v2f* wb = (const v2f*)(w2 + (o*2+1)*8);
    v2f va = splat2(v0), vb = splat2(v1);
    #pragma unroll
    for(int t=0;t<4;t++) acc[t] += va*wa[t];
    #pragma unroll
    for(int t=0;t<4;t++) acc[t] += vb*wb[t];
  }
  v2f* lg2 = (v2f*)(logits + (size_t)e*8);
  #pragma unroll
  for(int q=0;q<4;q++) lg2[q] = acc[q];
}

// ---------------- K7: softmax + aggregate (float4 gather) + o_w + FFN + fused norm ----------------
// R2-proven version: wave-private LDS, NO barriers.
__global__ __launch_bounds__(256) void k_update(const int* __restrict__ nbr, const float* __restrict__ xl,
                         const float* __restrict__ logits, float* __restrict__ x,
                         float* __restrict__ xlout,
                         const float* __restrict__ vw, const float* __restrict__ ow,
                         const float* __restrict__ fw1, const float* __restrict__ fw2,
                         const float* __restrict__ fwg, const float* __restrict__ fv1,
                         const float* __restrict__ g0, const float* __restrict__ b0,
                         const float* __restrict__ g1){
  __shared__ float S_lg[4][240], S_m[4][8], S_inv[4][8];
  __shared__ float S_S[4][1024], S_agg[4][512], S_x[4][128];
  __shared__ float S_h[4][64], S_g[4][32], S_d0[4][32];
  int g = threadIdx.x>>6, t = threadIdx.x&63;
  int n = blockIdx.x*4 + g;
  for(int r=t; r<240; r+=64) S_lg[g][r] = logits[(size_t)n*240+r];
  if(t<8){
    float m=-1e30f;
    for(int kk=0;kk<KNB;kk++) m=fmaxf(m, S_lg[g][kk*8+t]);
    float s=0.f;
    for(int kk=0;kk<KNB;kk++) s += __expf(S_lg[g][kk*8+t]-m);
    S_m[g][t]=m; S_inv[g][t]=1.0f/s;
  }
  for(int r=t; r<240; r+=64){ int h=r&7; S_lg[g][r]=__expf(S_lg[g][r]-S_m[g][h])*S_inv[g][h]; }
  int hd = t>>3, i8 = t&7;
  const float4* xl4 = (const float4*)xl;
  float acc[16];
  for(int m=0;m<16;m++) acc[m]=0.f;
  for(int kk=0;kk<KNB;kk++){
    int j=nbr[n*KNB+kk];
    float a = S_lg[g][kk*8+hd];
    float4 b0v = xl4[j*32 + i8*4 + 0];
    float4 b1v = xl4[j*32 + i8*4 + 1];
    float4 b2v = xl4[j*32 + i8*4 + 2];
    float4 b3v = xl4[j*32 + i8*4 + 3];
    acc[0]+=a*b0v.x; acc[1]+=a*b0v.y; acc[2]+=a*b0v.z; acc[3]+=a*b0v.w;
    acc[4]+=a*b1v.x; acc[5]+=a*b1v.y; acc[6]+=a*b1v.z; acc[7]+=a*b1v.w;
    acc[8]+=a*b2v.x; acc[9]+=a*b2v.y; acc[10]+=a*b2v.z; acc[11]+=a*b2v.w;
    acc[12]+=a*b3v.x; acc[13]+=a*b3v.y; acc[14]+=a*b3v.z; acc[15]+=a*b3v.w;
  }
  for(int m=0;m<16;m++) S_S[g][hd*128 + i8*16 + m] = acc[m];
  for(int half=0; half<2; half++){
    int hv = half*64+t;
    int hh = hv>>4;
    float a0=0.f,a1=0.f,a2=0.f,a3=0.f;
    for(int c=0;c<32;c++){
      float w = vw[c*128+hv];
      a0 += S_S[g][hh*128 + c]*w;
      a1 += S_S[g][hh*128 + 32+c]*w;
      a2 += S_S[g][hh*128 + 64+c]*w;
      a3 += S_S[g][hh*128 + 96+c]*w;
    }
    S_agg[g][hv]=a0; S_agg[g][128+hv]=a1; S_agg[g][256+hv]=a2; S_agg[g][384+hv]=a3;
  }
  for(int half=0; half<2; half++){
    int e = half*64+t;
    int rrow = e>>5, c = e&31;
    float v = x[n*128+e];
    for(int hv=0;hv<128;hv++) v += S_agg[g][rrow*128+hv]*ow[hv*32+c];
    S_x[g][e]=v;
  }
  {
    float hs=0.f;
    for(int c=0;c<32;c++) hs += S_x[g][c]*fw1[c*64+t];
    S_h[g][t]=siluf(hs);
  }
  if(t<32){
    float gs=0.f, d0=0.f;
    for(int c=0;c<64;c++){ float hv=S_h[g][c]; gs += hv*fwg[c*32+t]; d0 += hv*fw2[c*32+t]; }
    S_g[g][t]=1.0f/(1.0f+__expf(-gs));
    S_d0[g][t]=d0;
  }
  for(int half=0; half<2; half++){
    int e = half*64+t;
    int rrow = e>>5, c = e&31;
    float xv = S_x[g][e], outv;
    if(rrow==0){ outv = xv + S_d0[g][c]; }
    else {
      float dv=0.f;
      for(int cc=0;cc<32;cc++) dv += S_x[g][rrow*32+cc]*fv1[cc*32+c];
      outv = xv + dv*S_g[g][c];
    }
    S_x[g][e]=outv;
    x[n*128+e]=outv;
  }
  if(t<32){
    float x0=S_x[g][t];
    float s=x0, s2=x0*x0;
    for(int off=16; off>0; off>>=1){ s+=__shfl_xor(s,off,32); s2+=__shfl_xor(s2,off,32); }
    float mu=s*(1.0f/32.0f), var=s2*(1.0f/32.0f)-mu*mu;
    float y0=(x0-mu)*rsqrtf(var+1e-6f)*g0[t]+b0[t];
    float v1=S_x[g][32+t], v2=S_x[g][64+t], v3=S_x[g][96+t];
    float ss=v1*v1+v2*v2+v3*v3;
    for(int off=16; off>0; off>>=1) ss+=__shfl_xor(ss,off,32);
    float sc=rsqrtf(ss*(1.0f/96.0f)+1e-6f);
    float gg=g1[t];
    xlout[n*128+t]=y0; xlout[n*128+32+t]=v1*sc*gg;
    xlout[n*128+64+t]=v2*sc*gg; xlout[n*128+96+t]=v3*sc*gg;
  }
}

// ---------------- K8: edge update + next-layer logits (layers 0..2) ----------------
// Spill-free: o-dim quartered (h=16 live), per-edge ef row staged in padded LDS
// ([128][33]: 2-way bank aliasing = free). Summation orders unchanged -> bit-identical.
__global__ __launch_bounds__(128, 4)
void k_efup(const int* __restrict__ nbr,
            const float* __restrict__ hsrc, const float* __restrict__ hdst,
            const float* __restrict__ ew1, const float* __restrict__ ew2,
            float* __restrict__ ef,
            const float* __restrict__ asrc, const float* __restrict__ adst,
            const float* __restrict__ aw1n, const float* __restrict__ aw2n,
            float* __restrict__ logits){
  __shared__ float Sf[128][33];
  int tl = threadIdx.x;
  int e = blockIdx.x*128 + tl;
  int n = e/KNB;
  int j = nbr[e];
  // stage this edge's ef row into LDS (b32 writes, conflict-free)
  {
    const float4* s4 = (const float4*)(ef + (size_t)e*32);
    #pragma unroll
    for(int q=0;q<8;q++){
      float4 v = s4[q];
      Sf[tl][q*4+0]=v.x; Sf[tl][q*4+1]=v.y; Sf[tl][q*4+2]=v.z; Sf[tl][q*4+3]=v.w;
    }
  }
  v2f acc[16];
  #pragma unroll
  for(int t=0;t<16;t++) acc[t]=splat2(0.f);
  #pragma unroll
  for(int oq=0; oq<4; oq++){
    v2f h[8];
    {
      const float4* pj = (const float4*)(hsrc + (size_t)j*64 + oq*16);
      const float4* pn = (const float4*)(hdst + (size_t)n*64 + oq*16);
      #pragma unroll
      for(int q=0;q<4;q++){
        float4 a=pj[q], b=pn[q];
        h[2*q]   = (v2f){a.x+b.x, a.y+b.y};
        h[2*q+1] = (v2f){a.z+b.z, a.w+b.w};
      }
    }
    #pragma unroll
    for(int c=0;c<32;c++){
      v2f fc = splat2(Sf[tl][c]);
      const v2f* w = (const v2f*)(ew1 + c*64 + oq*16);
      #pragma unroll
      for(int o=0;o<8;o++) h[o] += fc*w[o];
    }
    #pragma unroll
    for(int o=0;o<8;o++){
      float v0 = siluf(h[o].x), v1 = siluf(h[o].y);
      const v2f* wa = (const v2f*)(ew2 + (oq*16+o*2)*32);
      const v2f* wb = (const v2f*)(ew2 + (oq*16+o*2+1)*32);
      v2f va = splat2(v0), vb = splat2(v1);
      #pragma unroll
      for(int t=0;t<16;t++) acc[t] += va*wa[t];
      #pragma unroll
      for(int t=0;t<16;t++) acc[t] += vb*wb[t];
    }
  }
  // residual: fn = f_old + acc; write to global and back into LDS (for logits)
  {
    float4* e4 = (float4*)(ef + (size_t)e*32);
    #pragma unroll
    for(int q=0;q<8;q++){
      float f0 = Sf[tl][q*4+0] + acc[2*q].x;
      float f1 = Sf[tl][q*4+1] + acc[2*q].y;
      float f2 = Sf[tl][q*4+2] + acc[2*q+1].x;
      float f3 = Sf[tl][q*4+3] + acc[2*q+1].y;
      e4[q] = make_float4(f0,f1,f2,f3);
      Sf[tl][q*4+0]=f0; Sf[tl][q*4+1]=f1; Sf[tl][q*4+2]=f2; Sf[tl][q*4+3]=f3;
    }
  }
  // next-layer logits on (asrc[j]+adst[n], new ef)
  v2f h2[16];
  {
    const v2f* pj = (const v2f*)(asrc + (size_t)j*32);
    const v2f* pn = (const v2f*)(adst + (size_t)n*32);
    #pragma unroll
    for(int q=0;q<16;q++) h2[q] = pj[q]+pn[q];
  }
  #pragma unroll
  for(int c=0;c<32;c++){
    v2f fc = splat2(Sf[tl][c]);
    const v2f* w = (const v2f*)(aw1n + (64+c)*32);
    #pragma unroll
    for(int o=0;o<16;o++) h2[o] += fc*w[o];
  }
  v2f a8[4];
  #pragma unroll
  for(int t=0;t<4;t++) a8[t]=splat2(0.f);
  #pragma unroll
  for(int o=0;o<16;o++){
    float v0 = siluf(h2[o].x), v1 = siluf(h2[o].y);
    const v2f* wa = (const v2f*)(aw2n + (o*2)*8);
    const v2f* wb = (const v2f*)(aw2n + (o*2+1)*8);
    v2f va = splat2(v0), vb = splat2(v1);
    #pragma unroll
    for(int t=0;t<4;t++) a8[t] += va*wa[t];
    #pragma unroll
    for(int t=0;t<4;t++) a8[t] += vb*wb[t];
  }
  v2f* lg2 = (v2f*)(logits + (size_t)e*8);
  #pragma unroll
  for(int q=0;q<4;q++) lg2[q] = a8[q];
}

// ---------------- K8b: layer-3 edge update + out radial MLP fused; spill-free LDS version ----------------
// Same structure as k_efup: ef row staged in padded LDS, o-dim quartered for BOTH MLPs.
// Layer-3 new ef lives only in LDS; orad written in-place over ef slot e (thread-owned).
__global__ __launch_bounds__(128, 4)
void k_efup_orad(const int* __restrict__ nbr,
                 const float* __restrict__ hsrc, const float* __restrict__ hdst,
                 const float* __restrict__ ew1, const float* __restrict__ ew2,
                 float* __restrict__ ef,
                 const float* __restrict__ orw1, const float* __restrict__ orw2){
  __shared__ float Sf[128][33];
  int tl = threadIdx.x;
  int e = blockIdx.x*128 + tl;
  int n = e/KNB;
  int j = nbr[e];
  // stage this edge's ef row into LDS
  {
    const float4* s4 = (const float4*)(ef + (size_t)e*32);
    #pragma unroll
    for(int q=0;q<8;q++){
      float4 v = s4[q];
      Sf[tl][q*4+0]=v.x; Sf[tl][q*4+1]=v.y; Sf[tl][q*4+2]=v.z; Sf[tl][q*4+3]=v.w;
    }
  }
  // ---- edge-update MLP: 32->64(silu)->32, o-quartered ----
  v2f acc[16];
  #pragma unroll
  for(int t=0;t<16;t++) acc[t]=splat2(0.f);
  #pragma unroll
  for(int oq=0; oq<4; oq++){
    v2f h[8];
    {
      const float4* pj = (const float4*)(hsrc + (size_t)j*64 + oq*16);
      const float4* pn = (const float4*)(hdst + (size_t)n*64 + oq*16);
      #pragma unroll
      for(int q=0;q<4;q++){
        float4 a=pj[q], b=pn[q];
        h[2*q]   = (v2f){a.x+b.x, a.y+b.y};
        h[2*q+1] = (v2f){a.z+b.z, a.w+b.w};
      }
    }
    #pragma unroll
    for(int c=0;c<32;c++){
      v2f fc = splat2(Sf[tl][c]);
      const v2f* w = (const v2f*)(ew1 + c*64 + oq*16);
      #pragma unroll
      for(int o=0;o<8;o++) h[o] += fc*w[o];
    }
    #pragma unroll
    for(int o=0;o<8;o++){
      float v0 = siluf(h[o].x), v1 = siluf(h[o].y);
      const v2f* wa = (const v2f*)(ew2 + (oq*16+o*2)*32);
      const v2f* wb = (const v2f*)(ew2 + (oq*16+o*2+1)*32);
      v2f va = splat2(v0), vb = splat2(v1);
      #pragma unroll
      for(int t=0;t<16;t++) acc[t] += va*wa[t];
      #pragma unroll
      for(int t=0;t<16;t++) acc[t] += vb*wb[t];
    }
  }
  // layer-3 new ef: residual into LDS only (no global write; sole consumer is orad MLP)
  #pragma unroll
  for(int q=0;q<16;q++){ Sf[tl][2*q] += acc[q].x; Sf[tl][2*q+1] += acc[q].y; }
  // ---- out radial MLP: 32->64(silu)->32 on new ef, o-quartered ----
  v2f oa[16];
  #pragma unroll
  for(int t=0;t<16;t++) oa[t]=splat2(0.f);
  #pragma unroll
  for(int oq=0; oq<4; oq++){
    v2f h[8];
    #pragma unroll
    for(int o=0;o<8;o++) h[o]=splat2(0.f);
    #pragma unroll
    for(int c=0;c<32;c++){
      v2f fc = splat2(Sf[tl][c]);
      const v2f* w = (const v2f*)(orw1 + c*64 + oq*16);
      #pragma unroll
      for(int o=0;o<8;o++) h[o] += fc*w[o];
    }
    #pragma unroll
    for(int o=0;o<8;o++){
      float v0 = siluf(h[o].x), v1 = siluf(h[o].y);
      const v2f* wa = (const v2f*)(orw2 + (oq*16+o*2)*32);
      const v2f* wb = (const v2f*)(orw2 + (oq*16+o*2+1)*32);
      v2f va = splat2(v0), vb = splat2(v1);
      #pragma unroll
      for(int t=0;t<16;t++) oa[t] += va*wa[t];
      #pragma unroll
      for(int t=0;t<16;t++) oa[t] += vb*wb[t];
    }
  }
  // in-place: thread e owns slot e of ef; write orad there (ef dead afterwards)
  v2f* r2 = (v2f*)(ef + (size_t)e*32);
  #pragma unroll
  for(int q=0;q<16;q++) r2[q] = oa[q];
}

// ---------------- K9: out gather + projection + fused seq head ----------------
__global__ __launch_bounds__(256) void k_out(const int* __restrict__ nbr, const float* __restrict__ orad,
                      const float* __restrict__ x,
                      const float* __restrict__ outw,
                      const float* __restrict__ sw1, const float* __restrict__ sb1,
                      const float* __restrict__ sw2, const float* __restrict__ sb2,
                      const float* __restrict__ sw3, const float* __restrict__ sb3,
                      float* __restrict__ out, float* __restrict__ outseq){
  __shared__ float msg[4][128];
  __shared__ float h1[4][64], h2[4][32], lgs[4][20];
  int g = threadIdx.x>>6, t = threadIdx.x&63;
  int n = blockIdx.x*4 + g;
  int t31 = t&31;
  float acc0=0.f, acc1=0.f;
  for(int kk=0;kk<KNB;kk++){
    int e=n*KNB+kk;
    int j=nbr[e];
    float rl = orad[(size_t)e*32 + t31];
    acc0 += x[j*128+t]*rl;
    acc1 += x[j*128+64+t]*rl;
  }
  msg[g][t]=acc0*(1.0f/KNB); msg[g][64+t]=acc1*(1.0f/KNB);
  for(int o=t;o<91;o+=64){
    for(int rrow=1;rrow<4;rrow++){
      float s=0.f;
      for(int c=0;c<32;c++) s += msg[g][rrow*32+c]*outw[c*91+o];
      out[(size_t)n*273 + o*3 + (rrow-1)] = s;
    }
  }
  {
    float s=0.f;
    for(int c=0;c<32;c++) s += x[n*128+c]*sw1[c*64+t];
    h1[g][t]=fmaxf(s+sb1[t],0.f);
  }
  if(t<32){
    float s=0.f;
    for(int c=0;c<64;c++) s += h1[g][c]*sw2[c*32+t];
    h2[g][t]=fmaxf(s+sb2[t],0.f);
  }
  if(t<20){
    float s=0.f;
    for(int c=0;c<32;c++) s += h2[g][c]*sw3[c*20+t];
    lgs[g][t]=s+sb3[t];
  }
  if(t<20){
    float m=-1e30f;
    for(int c=0;c<20;c++) m=fmaxf(m,lgs[g][c]);
    float se=0.f;
    for(int c=0;c<20;c++) se += __expf(lgs[g][c]-m);
    outseq[(size_t)n*20+t]=lgs[g][t]-m-logf(se);
  }
}

extern "C" void kernel_launch(void* const* d_in, const int* in_sizes, int n_in,
                              void* d_out, int out_size, void* d_ws, size_t ws_size,
                              hipStream_t stream) {
  const float* bb      = (const float*)d_in[0];
  const float* latent  = (const float*)d_in[1];
  const float* ln_g0   = (const float*)d_in[2];
  const float* ln_b0   = (const float*)d_in[3];
  const float* ln_g1   = (const float*)d_in[4];
  const float* bbw1    = (const float*)d_in[5];
  const float* bbw2    = (const float*)d_in[6];
  const float* bboutw  = (const float*)d_in[7];
  const float* latw1   = (const float*)d_in[8];
  const float* latw2   = (const float*)d_in[9];
  const float* latoutw = (const float*)d_in[10];
  const float* tg0     = (const float*)d_in[11];
  const float* tb0     = (const float*)d_in[12];
  const float* tg1     = (const float*)d_in[13];
  const float* aw1     = (const float*)d_in[14];
  const float* aw2     = (const float*)d_in[15];
  const float* vw      = (const float*)d_in[16];
  const float* ow      = (const float*)d_in[17];
  const float* fw1     = (const float*)d_in[18];
  const float* fw2     = (const float*)d_in[19];
  const float* fwg     = (const float*)d_in[20];
  const float* fv1     = (const float*)d_in[21];
  const float* ew1     = (const float*)d_in[22];
  const float* ew2     = (const float*)d_in[23];
  const float* orw1    = (const float*)d_in[24];
  const float* orw2    = (const float*)d_in[25];
  const float* outw    = (const float*)d_in[26];
  const float* sw1     = (const float*)d_in[27];
  const float* sb1     = (const float*)d_in[28];
  const float* sw2     = (const float*)d_in[29];
  const float* sb2     = (const float*)d_in[30];
  const float* sw3     = (const float*)d_in[31];
  const float* sb3     = (const float*)d_in[32];
  float* outp = (float*)d_out;

  // workspace layout (radbb overlays logits; radlat + nodeprep arrays overlay edgescratch;
  // tbl overlays xbuf (dead until k_init); orad written in-place over ef by k_efup_orad)
  int*    nbr    = (int*)d_ws;
  float*  ef     = (float*)((char*)d_ws + 1024*1024);
  float*  xbuf   = ef   + (size_t)NEDGE*32;
  float*  xlA    = xbuf + (size_t)NRES*128;
  float*  xlB    = xlA  + (size_t)NRES*128;
  float*  bbf    = xlB  + (size_t)NRES*128;
  float*  logits = bbf  + (size_t)NRES*28;
  float4* ca     = (float4*)(logits + (size_t)NEDGE*8);
  float*  edgescratch = (float*)(ca + NRES);     // NEDGE*32 floats
  float*  radbb  = logits;                       // NEDGE*8, dead before first k_logits
  float*  radlat = edgescratch;                  // NEDGE*32, dead after k_init
  float*  tbl    = xbuf;                         // 4096*16 floats, xbuf dead until k_init
  // per-node hoisted arrays: live only between k_init and k_efup_orad (radlat dead window)
  float*  hsrc   = edgescratch;                              // NRES*64
  float*  hdst   = edgescratch + (size_t)NRES*64;            // NRES*64
  float*  asrc   = edgescratch + (size_t)NRES*128;           // NRES*32
  float*  adst   = edgescratch + (size_t)NRES*128 + (size_t)NRES*32; // NRES*32

  k_bbfeat  <<<NRES/256, 256, 0, stream>>>(bb, bbf, ca);
  k_knn     <<<NRES/4,   256, 0, stream>>>(ca, nbr);
  k_tbl     <<<4096*8/256, 256, 0, stream>>>(tbl);
  k_edgefeat<<<NEDGE/256, 256, 0, stream>>>(ca, nbr, tbl, ef);
  k_norm    <<<NRES*32/256, 256, 0, stream>>>(latent, xlA, ln_g0, ln_b0, ln_g1);
  k_rad     <<<NEDGE/128, 128, 0, stream>>>(ef, bbw1, bbw2, latw1, latw2, radbb, radlat);
  k_init    <<<NRES/4, 256, 0, stream>>>(nbr, radbb, radlat, bbf, xlA,
                                         bboutw, latoutw,
                                         tg0, tb0, tg1,
                                         xbuf, xlB);
  // layer-0 logits: hoist xl halves, then per-edge ef part
  k_nodeprep<<<NRES/4, 256, 0, stream>>>(nullptr, xlB, ew1, aw1, hsrc, hdst, asrc, adst);
  k_logits  <<<NEDGE/128, 128, 0, stream>>>(nbr, asrc, adst, ef, aw1, aw2, logits);
  for(int l=0;l<4;l++){
    const float* xl_in  = (l&1) ? xlA : xlB;
    float*       xl_out = (l&1) ? xlB : xlA;
    int ln = (l+1<4) ? (l+1) : 3;
    k_update <<<NRES/4, 256, 0, stream>>>(nbr, xl_in, logits, xbuf, xl_out,
                                          vw+l*32*128, ow+l*128*32,
                                          fw1+l*32*64, fw2+l*64*32,
                                          fwg+l*64*32, fv1+l*32*32,
                                          tg0+ln*32, tb0+ln*32, tg1+ln*32);
    if(l<3){
      k_nodeprep<<<NRES/4, 256, 0, stream>>>(xbuf, xl_out, ew1+l*96*64, aw1+(l+1)*96*32,
                                             hsrc, hdst, asrc, adst);
      k_efup<<<NEDGE/128, 128, 0, stream>>>(nbr, hsrc, hdst,
                                            ew1+l*96*64, ew2+l*64*32, ef,
                                            asrc, adst,
                                            aw1+(l+1)*96*32, aw2+(l+1)*32*8, logits);
    } else {
      k_nodeprep<<<NRES/4, 256, 0, stream>>>(xbuf, xl_out, ew1+l*96*64, nullptr,
                                             hsrc, hdst, asrc, adst);
      k_efup_orad<<<NEDGE/128, 128, 0, stream>>>(nbr, hsrc, hdst,
                                                 ew1+l*96*64, ew2+l*64*32, ef,
                                                 orw1, orw2);
    }
  }
  k_out <<<NRES/4, 256, 0, stream>>>(nbr, ef /*orad in-place*/, xbuf, outw,
                                     sw1, sb1, sw2, sb2, sw3, sb3,
                                     outp, outp + (size_t)NRES*273);
}